// Round 8
// baseline (427.001 us; speedup 1.0000x reference)
//
#include <hip/hip_runtime.h>

// ---------------------------------------------------------------------------
// HeteroRGCN: 3x (RGCNConv mean-per-relation + ReLU + BN(eval)) + Linear
// Round 7: register-only MFMA GEMM via swapped operands (C^T frags -> direct
// coalesced stores, zero LDS/zero barriers), 4B packed CSR records, lin fused
// into last agg, merged weight-convert kernel.
// ---------------------------------------------------------------------------

#define R_REL 8

typedef unsigned short ushort_t;
typedef short short8 __attribute__((ext_vector_type(8)));
typedef float f32x4 __attribute__((ext_vector_type(4)));

#define MFMA(a, b, c) __builtin_amdgcn_mfma_f32_16x16x32_bf16(a, b, c, 0, 0, 0)

static __device__ __forceinline__ unsigned short f2bf(float f) {
    unsigned int u = __float_as_uint(f);
    u = (u + 0x7FFF + ((u >> 16) & 1)) >> 16;   // round-to-nearest-even
    return (unsigned short)u;
}
static __device__ __forceinline__ float bf2f(unsigned short h) {
    return __uint_as_float(((unsigned int)h) << 16);
}

// ---- merged weight convert + transpose: 6 arrays, f32 [G][K][64] -> bf16 [G][64][K]
struct WcvtA {
    const float* src[6];
    ushort_t*    dst[6];
    int          end[6];   // cumulative element counts
    int          K[6];
};
__global__ void wcvt6_kernel(WcvtA a, int total)
{
    int i = blockIdx.x * 256 + threadIdx.x;
    if (i >= total) return;
    int s = 0;
    while (i >= a.end[s]) ++s;
    int j = i - (s ? a.end[s - 1] : 0);
    int K = a.K[s];
    int g = j / (K * 64), rem = j % (K * 64), k = rem >> 6, c = rem & 63;
    a.dst[s][(size_t)g * 64 * K + (size_t)c * K + k] = f2bf(a.src[s][j]);
}

// ---- input convert: f32 -> bf16 (4 elems/thread)
__global__ void xcvt_kernel(const float* __restrict__ src, ushort_t* __restrict__ dst, int n4)
{
    int i = blockIdx.x * 256 + threadIdx.x;
    if (i >= n4) return;
    float4 v = ((const float4*)src)[i];
    ushort_t t[4] = {f2bf(v.x), f2bf(v.y), f2bf(v.z), f2bf(v.w)};
    *(uint2*)&dst[(size_t)i * 4] = *(const uint2*)t;
}

// ---- register-only MFMA GEMM.
// A [n x K] bf16 row-major. Per 64-row block: 4 waves (2x2 of 32x32).
// For r<8: C_r = A @ W_r^T(stored [64][K]) -> H bf16 (ld 512, colbase r*64).
// r==8: C = A @ RT + bias -> accb f32.
// Swapped mfma(b,a) yields C^T frags: lane fr = C row, 4 consecutive C cols/reg.
template<int K>
__global__ __launch_bounds__(256)
void mgemm2_kernel(const ushort_t* __restrict__ A, int n,
                   const ushort_t* __restrict__ WT, const ushort_t* __restrict__ RT,
                   const float* __restrict__ bias,
                   ushort_t* __restrict__ H, float* __restrict__ accb)
{
    constexpr int KS = K / 32;
    const int tid = threadIdx.x;
    const int wid = tid >> 6, lane = tid & 63;
    const int wr = (wid >> 1) << 5;      // wave row offset: 0/32
    const int wc = (wid & 1) << 5;       // wave col offset: 0/32
    const int fr = lane & 15;
    const int kg = (lane >> 4) << 3;     // k sub-offset 0/8/16/24
    const int cq = (lane >> 4) << 2;     // col quad 0/4/8/12
    const int row0 = blockIdx.x * 64;

    // A fragments: rows row0+wr+m*16+fr, k = ks*32+kg  (held across all 9 outputs)
    short8 a[2][KS];
    #pragma unroll
    for (int m = 0; m < 2; ++m) {
        int rr = row0 + wr + m * 16 + fr;
        if (rr < n) {
            #pragma unroll
            for (int ks = 0; ks < KS; ++ks)
                a[m][ks] = *(const short8*)&A[(size_t)rr * K + ks * 32 + kg];
        } else {
            #pragma unroll
            for (int ks = 0; ks < KS; ++ks)
                a[m][ks] = short8{0, 0, 0, 0, 0, 0, 0, 0};
        }
    }

    for (int r = 0; r < 9; ++r) {
        const ushort_t* B = (r < R_REL) ? (WT + (size_t)r * 64 * K) : RT;

        short8 b[2][KS];
        #pragma unroll
        for (int nn = 0; nn < 2; ++nn)
            #pragma unroll
            for (int ks = 0; ks < KS; ++ks)
                b[nn][ks] = *(const short8*)&B[(size_t)(wc + nn * 16 + fr) * K + ks * 32 + kg];

        f32x4 acc[2][2];   // [nn][m]
        if (r == R_REL) {
            #pragma unroll
            for (int nn = 0; nn < 2; ++nn) {
                float4 bv = *(const float4*)&bias[wc + nn * 16 + cq];
                acc[nn][0] = f32x4{bv.x, bv.y, bv.z, bv.w};
                acc[nn][1] = acc[nn][0];
            }
        } else {
            acc[0][0] = f32x4{0.f, 0.f, 0.f, 0.f};
            acc[0][1] = acc[0][0]; acc[1][0] = acc[0][0]; acc[1][1] = acc[0][0];
        }

        #pragma unroll
        for (int ks = 0; ks < KS; ++ks)
            #pragma unroll
            for (int nn = 0; nn < 2; ++nn)
                #pragma unroll
                for (int m = 0; m < 2; ++m)
                    acc[nn][m] = MFMA(b[nn][ks], a[m][ks], acc[nn][m]);

        // lane reg j of acc[nn][m] = C[row0+wr+m*16+fr][wc+nn*16+cq+j]
        #pragma unroll
        for (int m = 0; m < 2; ++m) {
            int rr = row0 + wr + m * 16 + fr;
            if (rr >= n) continue;
            #pragma unroll
            for (int nn = 0; nn < 2; ++nn) {
                if (r < R_REL) {
                    ushort_t t[4] = {f2bf(acc[nn][m][0]), f2bf(acc[nn][m][1]),
                                     f2bf(acc[nn][m][2]), f2bf(acc[nn][m][3])};
                    *(uint2*)&H[(size_t)rr * 512 + (r << 6) + wc + nn * 16 + cq] =
                        *(const uint2*)t;
                } else {
                    *(float4*)&accb[(size_t)rr * 64 + wc + nn * 16 + cq] =
                        make_float4(acc[nn][m][0], acc[nn][m][1],
                                    acc[nn][m][2], acc[nn][m][3]);
                }
            }
        }
    }
}

// ---- CSR build -------------------------------------------------------------
__global__ void count_kernel(const int* __restrict__ ei, const int* __restrict__ et,
                             int* __restrict__ cnt, int E)
{
    int e = blockIdx.x * 256 + threadIdx.x;
    if (e < E) atomicAdd(&cnt[(size_t)ei[E + e] * R_REL + et[e]], 1);
}

__global__ void invdeg_kernel(float* __restrict__ inv, int* __restrict__ deg, int N)
{
    int i = blockIdx.x * 256 + threadIdx.x;
    if (i >= N) return;
    const int* c = (const int*)inv;
    int tot = 0;
    float out[R_REL];
    #pragma unroll
    for (int r = 0; r < R_REL; ++r) {
        int cc = c[i * R_REL + r];
        tot += cc;
        out[r] = 1.0f / (float)(cc > 1 ? cc : 1);
    }
    #pragma unroll
    for (int r = 0; r < R_REL; ++r) inv[i * R_REL + r] = out[r];
    deg[i] = tot;
}

__global__ void scan1_kernel(const int* __restrict__ deg, int* __restrict__ offs,
                             int* __restrict__ partials, int N)
{
    __shared__ int sm[256];
    int i = blockIdx.x * 256 + threadIdx.x;
    int c = (i < N) ? deg[i] : 0;
    sm[threadIdx.x] = c;
    __syncthreads();
    for (int off = 1; off < 256; off <<= 1) {
        int t = (threadIdx.x >= off) ? sm[threadIdx.x - off] : 0;
        __syncthreads();
        sm[threadIdx.x] += t;
        __syncthreads();
    }
    if (i < N) offs[i] = sm[threadIdx.x] - c;
    if (threadIdx.x == 255) partials[blockIdx.x] = sm[255];
}

__global__ void scan2_kernel(int* __restrict__ partials, int P)
{
    __shared__ int sm[256];
    __shared__ int carry;
    if (threadIdx.x == 0) carry = 0;
    __syncthreads();
    for (int base = 0; base < P; base += 256) {
        int i = base + threadIdx.x;
        int c = (i < P) ? partials[i] : 0;
        sm[threadIdx.x] = c;
        __syncthreads();
        for (int off = 1; off < 256; off <<= 1) {
            int t = (threadIdx.x >= off) ? sm[threadIdx.x - off] : 0;
            __syncthreads();
            sm[threadIdx.x] += t;
            __syncthreads();
        }
        int incl = sm[threadIdx.x];
        int cold = carry;
        if (i < P) partials[i] = incl - c + cold;
        __syncthreads();
        if (threadIdx.x == 0) carry = cold + sm[255];
        __syncthreads();
    }
}

__global__ void scan3_kernel(int* __restrict__ offs, const int* __restrict__ partials, int N)
{
    int i = blockIdx.x * 256 + threadIdx.x;
    if (i < N) offs[i] += partials[blockIdx.x];
}

// scatter: ep[pos] = src | (r<<16)   (src < 65536, r < 8)
__global__ void fill4_kernel(const int* __restrict__ ei, const int* __restrict__ et,
                             const int* __restrict__ offs, int* __restrict__ cursor,
                             int* __restrict__ ep, int E)
{
    int e = blockIdx.x * 256 + threadIdx.x;
    if (e >= E) return;
    int d = ei[E + e];
    int pos = offs[d] + atomicAdd(&cursor[d], 1);
    ep[pos] = ei[e] | (et[e] << 16);
}

// ---- one wave per dst, 4 edges in flight (16-lane subgroups, uint2/lane),
// shfl_xor reduce, fused ReLU+BN; last layer additionally fuses final linear.
__global__ __launch_bounds__(256)
void agg4_kernel(const int* __restrict__ ep,
                 const int* __restrict__ offs, const int* __restrict__ deg,
                 const ushort_t* __restrict__ H, const float* __restrict__ accb,
                 const float* __restrict__ inv,
                 const float* __restrict__ g, const float* __restrict__ b,
                 const float* __restrict__ rm, const float* __restrict__ rv,
                 ushort_t* __restrict__ xout,
                 const float* __restrict__ Wl, const float* __restrict__ bl,
                 float* __restrict__ out, int N, int last)
{
    const int lane = threadIdx.x & 63;
    const int d = (blockIdx.x * 256 + threadIdx.x) >> 6;
    if (d >= N) return;

    const int sub = lane >> 4;
    const int fl  = lane & 15;
    const int n0 = offs[d];
    const int dg = deg[d];
    const float* invd = &inv[(size_t)d * R_REL];

    float s0 = 0.f, s1 = 0.f, s2 = 0.f, s3 = 0.f;
    int k = 0;

    for (; k + 8 <= dg; k += 8) {
        int pA = ep[n0 + k + sub];
        int pB = ep[n0 + k + 4 + sub];
        uint2 hA = *(const uint2*)&H[(size_t)(pA & 0xFFFF) * 512 + ((pA >> 16) << 6) + (fl << 2)];
        uint2 hB = *(const uint2*)&H[(size_t)(pB & 0xFFFF) * 512 + ((pB >> 16) << 6) + (fl << 2)];
        float wA = invd[pA >> 16];
        float wB = invd[pB >> 16];
        s0 += bf2f((ushort_t)(hA.x & 0xFFFF)) * wA + bf2f((ushort_t)(hB.x & 0xFFFF)) * wB;
        s1 += bf2f((ushort_t)(hA.x >> 16))    * wA + bf2f((ushort_t)(hB.x >> 16))    * wB;
        s2 += bf2f((ushort_t)(hA.y & 0xFFFF)) * wA + bf2f((ushort_t)(hB.y & 0xFFFF)) * wB;
        s3 += bf2f((ushort_t)(hA.y >> 16))    * wA + bf2f((ushort_t)(hB.y >> 16))    * wB;
    }
    for (; k + 4 <= dg; k += 4) {
        int pA = ep[n0 + k + sub];
        uint2 hA = *(const uint2*)&H[(size_t)(pA & 0xFFFF) * 512 + ((pA >> 16) << 6) + (fl << 2)];
        float wA = invd[pA >> 16];
        s0 += bf2f((ushort_t)(hA.x & 0xFFFF)) * wA;
        s1 += bf2f((ushort_t)(hA.x >> 16))    * wA;
        s2 += bf2f((ushort_t)(hA.y & 0xFFFF)) * wA;
        s3 += bf2f((ushort_t)(hA.y >> 16))    * wA;
    }
    if (k < dg && sub < dg - k) {
        int pA = ep[n0 + k + sub];
        uint2 hA = *(const uint2*)&H[(size_t)(pA & 0xFFFF) * 512 + ((pA >> 16) << 6) + (fl << 2)];
        float wA = invd[pA >> 16];
        s0 += bf2f((ushort_t)(hA.x & 0xFFFF)) * wA;
        s1 += bf2f((ushort_t)(hA.x >> 16))    * wA;
        s2 += bf2f((ushort_t)(hA.y & 0xFFFF)) * wA;
        s3 += bf2f((ushort_t)(hA.y >> 16))    * wA;
    }

    s0 += __shfl_xor(s0, 16); s1 += __shfl_xor(s1, 16);
    s2 += __shfl_xor(s2, 16); s3 += __shfl_xor(s3, 16);
    s0 += __shfl_xor(s0, 32); s1 += __shfl_xor(s1, 32);
    s2 += __shfl_xor(s2, 32); s3 += __shfl_xor(s3, 32);

    // ReLU + BN (all lanes; broadcast loads across the 4 subgroups)
    const int c4 = fl << 2;
    float4 aq = *(const float4*)&accb[(size_t)d * 64 + c4];
    float4 gm = *(const float4*)&g[c4];
    float4 bt = *(const float4*)&b[c4];
    float4 mu = *(const float4*)&rm[c4];
    float4 vr = *(const float4*)&rv[c4];
    float t0 = aq.x + s0, t1 = aq.y + s1, t2 = aq.z + s2, t3 = aq.w + s3;
    t0 = t0 > 0.f ? t0 : 0.f;  t1 = t1 > 0.f ? t1 : 0.f;
    t2 = t2 > 0.f ? t2 : 0.f;  t3 = t3 > 0.f ? t3 : 0.f;
    t0 = (t0 - mu.x) * rsqrtf(vr.x + 1e-5f) * gm.x + bt.x;
    t1 = (t1 - mu.y) * rsqrtf(vr.y + 1e-5f) * gm.y + bt.y;
    t2 = (t2 - mu.z) * rsqrtf(vr.z + 1e-5f) * gm.z + bt.z;
    t3 = (t3 - mu.w) * rsqrtf(vr.w + 1e-5f) * gm.w + bt.w;

    if (!last) {
        if (sub == 0) {
            ushort_t o[4] = {f2bf(t0), f2bf(t1), f2bf(t2), f2bf(t3)};
            *(uint2*)&xout[(size_t)d * 64 + c4] = *(const uint2*)o;
        }
    } else {
        // fused final linear: lane (sub,fl) accumulates its 4 features
        // (k = 4*fl+i) into outputs c = 4*sub..4*sub+3, then reduce over fl.
        float p0 = 0.f, p1 = 0.f, p2 = 0.f, p3 = 0.f;
        float tt[4] = {t0, t1, t2, t3};
        #pragma unroll
        for (int i = 0; i < 4; ++i) {
            float4 wv = *(const float4*)&Wl[(size_t)(c4 + i) * 16 + (sub << 2)];
            p0 += tt[i] * wv.x; p1 += tt[i] * wv.y;
            p2 += tt[i] * wv.z; p3 += tt[i] * wv.w;
        }
        #pragma unroll
        for (int m = 1; m < 16; m <<= 1) {
            p0 += __shfl_xor(p0, m); p1 += __shfl_xor(p1, m);
            p2 += __shfl_xor(p2, m); p3 += __shfl_xor(p3, m);
        }
        if (fl == 0) {
            float4 bv = *(const float4*)&bl[sub << 2];
            *(float4*)&out[(size_t)d * 16 + (sub << 2)] =
                make_float4(p0 + bv.x, p1 + bv.y, p2 + bv.z, p3 + bv.w);
        }
    }
}

extern "C" void kernel_launch(void* const* d_in, const int* in_sizes, int n_in,
                              void* d_out, int out_size, void* d_ws, size_t ws_size,
                              hipStream_t stream)
{
    const float* x  = (const float*)d_in[0];
    const int*   ei = (const int*)d_in[1];
    const int*   et = (const int*)d_in[2];
    const float* W[3]    = {(const float*)d_in[3], (const float*)d_in[6], (const float*)d_in[9]};
    const float* root[3] = {(const float*)d_in[4], (const float*)d_in[7], (const float*)d_in[10]};
    const float* bias[3] = {(const float*)d_in[5], (const float*)d_in[8], (const float*)d_in[11]};
    const float* gamma[3] = {(const float*)d_in[12], (const float*)d_in[16], (const float*)d_in[20]};
    const float* beta[3]  = {(const float*)d_in[13], (const float*)d_in[17], (const float*)d_in[21]};
    const float* rm[3]    = {(const float*)d_in[14], (const float*)d_in[18], (const float*)d_in[22]};
    const float* rv[3]    = {(const float*)d_in[15], (const float*)d_in[19], (const float*)d_in[23]};
    const float* Wl = (const float*)d_in[24];
    const float* bl = (const float*)d_in[25];

    const int N = in_sizes[0] / 128;
    const int E = in_sizes[2];
    const int K1 = 128;

    // ---- workspace layout (all 16B aligned) ----
    char* p = (char*)d_ws;
    float*   inv  = (float*)p;    p += (size_t)N * R_REL * 4;
    ushort_t* Hbuf = (ushort_t*)p; p += (size_t)N * 512 * 2;
    float*   accb = (float*)p;    p += (size_t)N * 64 * 4;
    ushort_t* xb  = (ushort_t*)p; p += (size_t)N * 64 * 2;
    ushort_t* x16 = (ushort_t*)p; p += (size_t)N * K1 * 2;
    ushort_t* wt0 = (ushort_t*)p; p += (size_t)R_REL * 64 * K1 * 2;
    ushort_t* wt1 = (ushort_t*)p; p += (size_t)R_REL * 64 * 64 * 2;
    ushort_t* wt2 = (ushort_t*)p; p += (size_t)R_REL * 64 * 64 * 2;
    ushort_t* rt0 = (ushort_t*)p; p += (size_t)64 * K1 * 2;
    ushort_t* rt1 = (ushort_t*)p; p += (size_t)64 * 64 * 2;
    ushort_t* rt2 = (ushort_t*)p; p += (size_t)64 * 64 * 2;
    int*   offs    = (int*)p;     p += (size_t)N * 4;
    int*   deg     = (int*)p;     p += (size_t)N * 4;
    int*   cursor  = (int*)p;     p += (size_t)N * 4;
    int*   ep      = (int*)p;     p += (size_t)E * 4;
    int*   partials = (int*)p;

    const ushort_t* wt[3] = {wt0, wt1, wt2};
    const ushort_t* rt[3] = {rt0, rt1, rt2};

    const int gxN = (N + 255) / 256;

    // ---- weight conversion (one kernel) + input conversion ----
    {
        WcvtA a;
        a.src[0] = W[0];   a.dst[0] = wt0; a.K[0] = K1;
        a.src[1] = W[1];   a.dst[1] = wt1; a.K[1] = 64;
        a.src[2] = W[2];   a.dst[2] = wt2; a.K[2] = 64;
        a.src[3] = root[0]; a.dst[3] = rt0; a.K[3] = K1;
        a.src[4] = root[1]; a.dst[4] = rt1; a.K[4] = 64;
        a.src[5] = root[2]; a.dst[5] = rt2; a.K[5] = 64;
        int sizes[6] = {R_REL * K1 * 64, R_REL * 64 * 64, R_REL * 64 * 64,
                        K1 * 64, 64 * 64, 64 * 64};
        int acc = 0;
        for (int i = 0; i < 6; ++i) { acc += sizes[i]; a.end[i] = acc; }
        wcvt6_kernel<<<(acc + 255) / 256, 256, 0, stream>>>(a, acc);
    }
    xcvt_kernel<<<((N * K1 / 4) + 255) / 256, 256, 0, stream>>>(x, x16, N * K1 / 4);

    // ---- CSR build ----
    hipMemsetAsync(inv, 0, (size_t)N * R_REL * 4, stream);
    hipMemsetAsync(cursor, 0, (size_t)N * 4, stream);
    count_kernel<<<(E + 255) / 256, 256, 0, stream>>>(ei, et, (int*)inv, E);
    invdeg_kernel<<<gxN, 256, 0, stream>>>(inv, deg, N);
    scan1_kernel<<<gxN, 256, 0, stream>>>(deg, offs, partials, N);
    scan2_kernel<<<1, 256, 0, stream>>>(partials, gxN);
    scan3_kernel<<<gxN, 256, 0, stream>>>(offs, partials, N);
    fill4_kernel<<<(E + 255) / 256, 256, 0, stream>>>(ei, et, offs, cursor, ep, E);

    // ---- 3 RGCN layers ----
    const int gx = (N + 63) / 64;
    const int gagg = (N * 64 + 255) / 256;
    const ushort_t* cur = x16;
    for (int layer = 0; layer < 3; ++layer) {
        if (layer == 0)
            mgemm2_kernel<128><<<gx, 256, 0, stream>>>(
                cur, N, wt[0], rt[0], bias[0], Hbuf, accb);
        else
            mgemm2_kernel<64><<<gx, 256, 0, stream>>>(
                cur, N, wt[layer], rt[layer], bias[layer], Hbuf, accb);
        int last = (layer == 2);
        agg4_kernel<<<gagg, 256, 0, stream>>>(
            ep, offs, deg, Hbuf, accb, inv,
            gamma[layer], beta[layer], rm[layer], rv[layer],
            xb, Wl, bl, (float*)d_out, N, last);
        cur = xb;
    }
}

// Round 9
// 413.308 us; speedup vs baseline: 1.0331x; 1.0331x over previous
//
#include <hip/hip_runtime.h>

// ---------------------------------------------------------------------------
// HeteroRGCN: 3x (RGCNConv mean-per-relation + ReLU + BN(eval)) + Linear
// Round 9: revert r8 regressions (int2 CSR records, sub0-only BN, LDS-Ct GEMM
// stores); keep lin fused into last agg (sub0 only), f32-A staging in layer-1
// mgemm (drops xcvt + x16 buffer), invdeg+scan1 fused.
// ---------------------------------------------------------------------------

#define R_REL 8

typedef unsigned short ushort_t;
typedef short short8 __attribute__((ext_vector_type(8)));
typedef float f32x4 __attribute__((ext_vector_type(4)));

#define MFMA(a, b, c) __builtin_amdgcn_mfma_f32_16x16x32_bf16(a, b, c, 0, 0, 0)

static __device__ __forceinline__ unsigned short f2bf(float f) {
    unsigned int u = __float_as_uint(f);
    u = (u + 0x7FFF + ((u >> 16) & 1)) >> 16;   // round-to-nearest-even
    return (unsigned short)u;
}
static __device__ __forceinline__ float bf2f(unsigned short h) {
    return __uint_as_float(((unsigned int)h) << 16);
}

// ---- merged weight convert + transpose: 6 arrays, f32 [G][K][64] -> bf16 [G][64][K]
struct WcvtA {
    const float* src[6];
    ushort_t*    dst[6];
    int          end[6];
    int          K[6];
};
__global__ void wcvt6_kernel(WcvtA a, int total)
{
    int i = blockIdx.x * 256 + threadIdx.x;
    if (i >= total) return;
    int s = 0;
    while (i >= a.end[s]) ++s;
    int j = i - (s ? a.end[s - 1] : 0);
    int K = a.K[s];
    int g = j / (K * 64), rem = j % (K * 64), k = rem >> 6, c = rem & 63;
    a.dst[s][(size_t)g * 64 * K + (size_t)c * K + k] = f2bf(a.src[s][j]);
}

// ---- MFMA GEMM (LDS-staged, Ct round-trip for full-line stores).
// A [n x K] row-major, f32 (AF32) or bf16; blockIdx.y<8: B=WT[y] -> H bf16
// (ld 512, colbase y*64); y==8: B=RT -> accb f32 + bias.
template<int K, bool AF32>
__global__ __launch_bounds__(256)
void mgemm_kernel(const void* __restrict__ Av, int n,
                  const ushort_t* __restrict__ WT, const ushort_t* __restrict__ RT,
                  const float* __restrict__ bias,
                  ushort_t* __restrict__ H, float* __restrict__ accb)
{
    __shared__ ushort_t As[64][136];
    __shared__ ushort_t Bs[64][136];

    const int row0 = blockIdx.x * 64;
    const int yr = blockIdx.y;
    const ushort_t* Bsrc = (yr < R_REL) ? (WT + (size_t)yr * 64 * K) : RT;

    const int tid = threadIdx.x;
    const int KB = K >> 3;

    for (int i = tid; i < 64 * KB; i += 256) {
        int r = i / KB, k8 = (i % KB) << 3;
        *(uint4*)&Bs[r][k8] = *(const uint4*)&Bsrc[(size_t)r * K + k8];
        if (AF32) {
            const float* Af = (const float*)Av;
            float4 f0 = make_float4(0.f, 0.f, 0.f, 0.f), f1 = f0;
            if (row0 + r < n) {
                f0 = *(const float4*)&Af[(size_t)(row0 + r) * K + k8];
                f1 = *(const float4*)&Af[(size_t)(row0 + r) * K + k8 + 4];
            }
            ushort_t t[8] = {f2bf(f0.x), f2bf(f0.y), f2bf(f0.z), f2bf(f0.w),
                             f2bf(f1.x), f2bf(f1.y), f2bf(f1.z), f2bf(f1.w)};
            *(uint4*)&As[r][k8] = *(const uint4*)t;
        } else {
            const ushort_t* Ab = (const ushort_t*)Av;
            uint4 av = make_uint4(0u, 0u, 0u, 0u);
            if (row0 + r < n) av = *(const uint4*)&Ab[(size_t)(row0 + r) * K + k8];
            *(uint4*)&As[r][k8] = av;
        }
    }
    __syncthreads();

    const int wid  = tid >> 6;
    const int lane = tid & 63;
    const int wr = (wid >> 1) << 5;
    const int wc = (wid & 1) << 5;
    const int fr = lane & 15;
    const int kg = (lane >> 4) << 3;

    f32x4 acc[2][2] = {};
    #pragma unroll
    for (int k0 = 0; k0 < K; k0 += 32) {
        short8 a0 = *(const short8*)&As[wr + fr     ][k0 + kg];
        short8 a1 = *(const short8*)&As[wr + 16 + fr][k0 + kg];
        short8 b0 = *(const short8*)&Bs[wc + fr     ][k0 + kg];
        short8 b1 = *(const short8*)&Bs[wc + 16 + fr][k0 + kg];
        acc[0][0] = MFMA(a0, b0, acc[0][0]);
        acc[0][1] = MFMA(a0, b1, acc[0][1]);
        acc[1][0] = MFMA(a1, b0, acc[1][0]);
        acc[1][1] = MFMA(a1, b1, acc[1][1]);
    }
    __syncthreads();

    float* Ct = (float*)As;            // [64][68] f32
    const int rbase = (lane >> 4) << 2;
    #pragma unroll
    for (int m = 0; m < 2; ++m)
        #pragma unroll
        for (int nn = 0; nn < 2; ++nn)
            #pragma unroll
            for (int j = 0; j < 4; ++j)
                Ct[(wr + m * 16 + rbase + j) * 68 + wc + nn * 16 + fr] = acc[m][nn][j];
    __syncthreads();

    if (yr < R_REL) {
        const int cb = yr << 6;
        for (int i = tid; i < 64 * 8; i += 256) {
            int r = i >> 3, c8 = (i & 7) << 3;
            if (row0 + r < n) {
                ushort_t t[8];
                #pragma unroll
                for (int j = 0; j < 8; ++j) t[j] = f2bf(Ct[r * 68 + c8 + j]);
                *(uint4*)&H[(size_t)(row0 + r) * 512 + cb + c8] = *(const uint4*)t;
            }
        }
    } else {
        for (int i = tid; i < 64 * 16; i += 256) {
            int r = i >> 4, c4 = (i & 15) << 2;
            if (row0 + r < n) {
                float4 o;
                o.x = Ct[r * 68 + c4 + 0] + bias[c4 + 0];
                o.y = Ct[r * 68 + c4 + 1] + bias[c4 + 1];
                o.z = Ct[r * 68 + c4 + 2] + bias[c4 + 2];
                o.w = Ct[r * 68 + c4 + 3] + bias[c4 + 3];
                *(float4*)&accb[(size_t)(row0 + r) * 64 + c4] = o;
            }
        }
    }
}

// ---- CSR build -------------------------------------------------------------
__global__ void count_kernel(const int* __restrict__ ei, const int* __restrict__ et,
                             int* __restrict__ cnt, int E)
{
    int e = blockIdx.x * 256 + threadIdx.x;
    if (e < E) atomicAdd(&cnt[(size_t)ei[E + e] * R_REL + et[e]], 1);
}

// counts -> inv (in place) + deg + block-local exclusive scan + partials
__global__ void invdeg_scan_kernel(float* __restrict__ inv, int* __restrict__ deg,
                                   int* __restrict__ offs, int* __restrict__ partials,
                                   int N)
{
    __shared__ int sm[256];
    int i = blockIdx.x * 256 + threadIdx.x;
    int tot = 0;
    if (i < N) {
        const int* c = (const int*)inv;
        float out[R_REL];
        #pragma unroll
        for (int r = 0; r < R_REL; ++r) {
            int cc = c[(size_t)i * R_REL + r];
            tot += cc;
            out[r] = 1.0f / (float)(cc > 1 ? cc : 1);
        }
        #pragma unroll
        for (int r = 0; r < R_REL; ++r) inv[(size_t)i * R_REL + r] = out[r];
        deg[i] = tot;
    }
    sm[threadIdx.x] = tot;
    __syncthreads();
    for (int off = 1; off < 256; off <<= 1) {
        int t = (threadIdx.x >= off) ? sm[threadIdx.x - off] : 0;
        __syncthreads();
        sm[threadIdx.x] += t;
        __syncthreads();
    }
    if (i < N) offs[i] = sm[threadIdx.x] - tot;
    if (threadIdx.x == 255) partials[blockIdx.x] = sm[255];
}

__global__ void scan2_kernel(int* __restrict__ partials, int P)
{
    __shared__ int sm[256];
    __shared__ int carry;
    if (threadIdx.x == 0) carry = 0;
    __syncthreads();
    for (int base = 0; base < P; base += 256) {
        int i = base + threadIdx.x;
        int c = (i < P) ? partials[i] : 0;
        sm[threadIdx.x] = c;
        __syncthreads();
        for (int off = 1; off < 256; off <<= 1) {
            int t = (threadIdx.x >= off) ? sm[threadIdx.x - off] : 0;
            __syncthreads();
            sm[threadIdx.x] += t;
            __syncthreads();
        }
        int incl = sm[threadIdx.x];
        int cold = carry;
        if (i < P) partials[i] = incl - c + cold;
        __syncthreads();
        if (threadIdx.x == 0) carry = cold + sm[255];
        __syncthreads();
    }
}

__global__ void scan3_kernel(int* __restrict__ offs, const int* __restrict__ partials, int N)
{
    int i = blockIdx.x * 256 + threadIdx.x;
    if (i < N) offs[i] += partials[blockIdx.x];
}

// scatter: ep[pos] = {src*512 + r*64, bits(1/cnt(dst,rel))}
__global__ void fill3_kernel(const int* __restrict__ ei, const int* __restrict__ et,
                             const int* __restrict__ offs, int* __restrict__ cursor,
                             const float* __restrict__ inv,
                             int2* __restrict__ ep, int E)
{
    int e = blockIdx.x * 256 + threadIdx.x;
    if (e >= E) return;
    int d = ei[E + e];
    int r = et[e];
    int pos = offs[d] + atomicAdd(&cursor[d], 1);
    ep[pos] = make_int2(ei[e] * 512 + r * 64,
                        __float_as_int(inv[(size_t)d * R_REL + r]));
}

// ---- one wave per dst, 8 edges in flight (16-lane subgroups, uint2/lane),
// shfl_xor reduce; sub0: ReLU+BN -> xout (bf16), or fused final linear (last).
__global__ __launch_bounds__(256)
void agg5_kernel(const int2* __restrict__ ep,
                 const int* __restrict__ offs, const int* __restrict__ deg,
                 const ushort_t* __restrict__ H, const float* __restrict__ accb,
                 const float* __restrict__ g, const float* __restrict__ b,
                 const float* __restrict__ rm, const float* __restrict__ rv,
                 ushort_t* __restrict__ xout,
                 const float* __restrict__ Wl, const float* __restrict__ bl,
                 float* __restrict__ out, int N, int last)
{
    const int lane = threadIdx.x & 63;
    const int d = (blockIdx.x * 256 + threadIdx.x) >> 6;
    if (d >= N) return;

    const int sub = lane >> 4;
    const int fl  = lane & 15;
    const int n0 = offs[d];
    const int dg = deg[d];

    float s0 = 0.f, s1 = 0.f, s2 = 0.f, s3 = 0.f;
    int k = 0;

    for (; k + 8 <= dg; k += 8) {
        int2 eA = ep[n0 + k + sub];
        int2 eB = ep[n0 + k + 4 + sub];
        uint2 hA = *(const uint2*)&H[(size_t)eA.x + (fl << 2)];
        uint2 hB = *(const uint2*)&H[(size_t)eB.x + (fl << 2)];
        float wA = __int_as_float(eA.y);
        float wB = __int_as_float(eB.y);
        s0 += bf2f((ushort_t)(hA.x & 0xFFFF)) * wA + bf2f((ushort_t)(hB.x & 0xFFFF)) * wB;
        s1 += bf2f((ushort_t)(hA.x >> 16))    * wA + bf2f((ushort_t)(hB.x >> 16))    * wB;
        s2 += bf2f((ushort_t)(hA.y & 0xFFFF)) * wA + bf2f((ushort_t)(hB.y & 0xFFFF)) * wB;
        s3 += bf2f((ushort_t)(hA.y >> 16))    * wA + bf2f((ushort_t)(hB.y >> 16))    * wB;
    }
    for (; k + 4 <= dg; k += 4) {
        int2 eA = ep[n0 + k + sub];
        uint2 hA = *(const uint2*)&H[(size_t)eA.x + (fl << 2)];
        float wA = __int_as_float(eA.y);
        s0 += bf2f((ushort_t)(hA.x & 0xFFFF)) * wA;
        s1 += bf2f((ushort_t)(hA.x >> 16))    * wA;
        s2 += bf2f((ushort_t)(hA.y & 0xFFFF)) * wA;
        s3 += bf2f((ushort_t)(hA.y >> 16))    * wA;
    }
    if (k < dg && sub < dg - k) {
        int2 eA = ep[n0 + k + sub];
        uint2 hA = *(const uint2*)&H[(size_t)eA.x + (fl << 2)];
        float wA = __int_as_float(eA.y);
        s0 += bf2f((ushort_t)(hA.x & 0xFFFF)) * wA;
        s1 += bf2f((ushort_t)(hA.x >> 16))    * wA;
        s2 += bf2f((ushort_t)(hA.y & 0xFFFF)) * wA;
        s3 += bf2f((ushort_t)(hA.y >> 16))    * wA;
    }

    s0 += __shfl_xor(s0, 16); s1 += __shfl_xor(s1, 16);
    s2 += __shfl_xor(s2, 16); s3 += __shfl_xor(s3, 16);
    s0 += __shfl_xor(s0, 32); s1 += __shfl_xor(s1, 32);
    s2 += __shfl_xor(s2, 32); s3 += __shfl_xor(s3, 32);

    if (sub == 0) {
        const int c4 = fl << 2;
        float4 aq = *(const float4*)&accb[(size_t)d * 64 + c4];
        float4 gm = *(const float4*)&g[c4];
        float4 bt = *(const float4*)&b[c4];
        float4 mu = *(const float4*)&rm[c4];
        float4 vr = *(const float4*)&rv[c4];
        float t0 = aq.x + s0, t1 = aq.y + s1, t2 = aq.z + s2, t3 = aq.w + s3;
        t0 = t0 > 0.f ? t0 : 0.f;  t1 = t1 > 0.f ? t1 : 0.f;
        t2 = t2 > 0.f ? t2 : 0.f;  t3 = t3 > 0.f ? t3 : 0.f;
        t0 = (t0 - mu.x) * rsqrtf(vr.x + 1e-5f) * gm.x + bt.x;
        t1 = (t1 - mu.y) * rsqrtf(vr.y + 1e-5f) * gm.y + bt.y;
        t2 = (t2 - mu.z) * rsqrtf(vr.z + 1e-5f) * gm.z + bt.z;
        t3 = (t3 - mu.w) * rsqrtf(vr.w + 1e-5f) * gm.w + bt.w;

        if (!last) {
            ushort_t o[4] = {f2bf(t0), f2bf(t1), f2bf(t2), f2bf(t3)};
            *(uint2*)&xout[(size_t)d * 64 + c4] = *(const uint2*)o;
        } else {
            // fused final linear: lane fl holds features c4..c4+3; accumulate
            // into 16 outputs, reduce over the 16 fl-lanes, lane 0 stores.
            f32x4 p[4] = {};
            float tt[4] = {t0, t1, t2, t3};
            #pragma unroll
            for (int i = 0; i < 4; ++i) {
                const float* wrow = &Wl[(size_t)(c4 + i) * 16];
                #pragma unroll
                for (int q = 0; q < 4; ++q)
                    p[q] += tt[i] * (*(const f32x4*)&wrow[q * 4]);
            }
            #pragma unroll
            for (int m = 1; m < 16; m <<= 1) {
                #pragma unroll
                for (int q = 0; q < 4; ++q) {
                    p[q][0] += __shfl_xor(p[q][0], m);
                    p[q][1] += __shfl_xor(p[q][1], m);
                    p[q][2] += __shfl_xor(p[q][2], m);
                    p[q][3] += __shfl_xor(p[q][3], m);
                }
            }
            if (fl == 0) {
                #pragma unroll
                for (int q = 0; q < 4; ++q) {
                    f32x4 bv = *(const f32x4*)&bl[q * 4];
                    f32x4 o = p[q] + bv;
                    *(f32x4*)&out[(size_t)d * 16 + q * 4] = o;
                }
            }
        }
    }
}

extern "C" void kernel_launch(void* const* d_in, const int* in_sizes, int n_in,
                              void* d_out, int out_size, void* d_ws, size_t ws_size,
                              hipStream_t stream)
{
    const float* x  = (const float*)d_in[0];
    const int*   ei = (const int*)d_in[1];
    const int*   et = (const int*)d_in[2];
    const float* W[3]    = {(const float*)d_in[3], (const float*)d_in[6], (const float*)d_in[9]};
    const float* root[3] = {(const float*)d_in[4], (const float*)d_in[7], (const float*)d_in[10]};
    const float* bias[3] = {(const float*)d_in[5], (const float*)d_in[8], (const float*)d_in[11]};
    const float* gamma[3] = {(const float*)d_in[12], (const float*)d_in[16], (const float*)d_in[20]};
    const float* beta[3]  = {(const float*)d_in[13], (const float*)d_in[17], (const float*)d_in[21]};
    const float* rm[3]    = {(const float*)d_in[14], (const float*)d_in[18], (const float*)d_in[22]};
    const float* rv[3]    = {(const float*)d_in[15], (const float*)d_in[19], (const float*)d_in[23]};
    const float* Wl = (const float*)d_in[24];
    const float* bl = (const float*)d_in[25];

    const int N = in_sizes[0] / 128;
    const int E = in_sizes[2];
    const int K1 = 128;

    // ---- workspace layout (all 16B aligned) ----
    char* p = (char*)d_ws;
    float*   inv  = (float*)p;    p += (size_t)N * R_REL * 4;
    ushort_t* Hbuf = (ushort_t*)p; p += (size_t)N * 512 * 2;
    float*   accb = (float*)p;    p += (size_t)N * 64 * 4;
    ushort_t* xb  = (ushort_t*)p; p += (size_t)N * 64 * 2;
    ushort_t* wt0 = (ushort_t*)p; p += (size_t)R_REL * 64 * K1 * 2;
    ushort_t* wt1 = (ushort_t*)p; p += (size_t)R_REL * 64 * 64 * 2;
    ushort_t* wt2 = (ushort_t*)p; p += (size_t)R_REL * 64 * 64 * 2;
    ushort_t* rt0 = (ushort_t*)p; p += (size_t)64 * K1 * 2;
    ushort_t* rt1 = (ushort_t*)p; p += (size_t)64 * 64 * 2;
    ushort_t* rt2 = (ushort_t*)p; p += (size_t)64 * 64 * 2;
    int*   offs    = (int*)p;     p += (size_t)N * 4;
    int*   deg     = (int*)p;     p += (size_t)N * 4;
    int*   cursor  = (int*)p;     p += (size_t)N * 4;
    int2*  ep      = (int2*)p;    p += (size_t)E * 8;
    int*   partials = (int*)p;

    const ushort_t* wt[3] = {wt0, wt1, wt2};
    const ushort_t* rt[3] = {rt0, rt1, rt2};

    const int gxN = (N + 255) / 256;

    // ---- weight conversion (one kernel) ----
    {
        WcvtA a;
        a.src[0] = W[0];   a.dst[0] = wt0; a.K[0] = K1;
        a.src[1] = W[1];   a.dst[1] = wt1; a.K[1] = 64;
        a.src[2] = W[2];   a.dst[2] = wt2; a.K[2] = 64;
        a.src[3] = root[0]; a.dst[3] = rt0; a.K[3] = K1;
        a.src[4] = root[1]; a.dst[4] = rt1; a.K[4] = 64;
        a.src[5] = root[2]; a.dst[5] = rt2; a.K[5] = 64;
        int sizes[6] = {R_REL * K1 * 64, R_REL * 64 * 64, R_REL * 64 * 64,
                        K1 * 64, 64 * 64, 64 * 64};
        int acc = 0;
        for (int i = 0; i < 6; ++i) { acc += sizes[i]; a.end[i] = acc; }
        wcvt6_kernel<<<(acc + 255) / 256, 256, 0, stream>>>(a, acc);
    }

    // ---- CSR build ----
    hipMemsetAsync(inv, 0, (size_t)N * R_REL * 4, stream);
    hipMemsetAsync(cursor, 0, (size_t)N * 4, stream);
    count_kernel<<<(E + 255) / 256, 256, 0, stream>>>(ei, et, (int*)inv, E);
    invdeg_scan_kernel<<<gxN, 256, 0, stream>>>(inv, deg, offs, partials, N);
    scan2_kernel<<<1, 256, 0, stream>>>(partials, gxN);
    scan3_kernel<<<gxN, 256, 0, stream>>>(offs, partials, N);
    fill3_kernel<<<(E + 255) / 256, 256, 0, stream>>>(ei, et, offs, cursor, inv, ep, E);

    // ---- 3 RGCN layers ----
    const int gx = (N + 63) / 64;
    const int gagg = (N * 64 + 255) / 256;
    const ushort_t* cur = nullptr;
    for (int layer = 0; layer < 3; ++layer) {
        if (layer == 0)
            mgemm_kernel<128, true><<<dim3(gx, R_REL + 1), 256, 0, stream>>>(
                (const void*)x, N, wt[0], rt[0], bias[0], Hbuf, accb);
        else
            mgemm_kernel<64, false><<<dim3(gx, R_REL + 1), 256, 0, stream>>>(
                (const void*)cur, N, wt[layer], rt[layer], bias[layer], Hbuf, accb);
        int last = (layer == 2);
        agg5_kernel<<<gagg, 256, 0, stream>>>(
            ep, offs, deg, Hbuf, accb,
            gamma[layer], beta[layer], rm[layer], rv[layer],
            xb, Wl, bl, (float*)d_out, N, last);
        cur = xb;
    }
}

// Round 10
// 406.024 us; speedup vs baseline: 1.0517x; 1.0179x over previous
//
#include <hip/hip_runtime.h>

// ---------------------------------------------------------------------------
// HeteroRGCN: 3x (RGCNConv mean-per-relation + ReLU + BN(eval)) + Linear
// Round 10: agg rewritten with lane-parallel coalesced edge-record prefetch +
// shfl broadcast (removes ep->H latency chain); template<LAST> split so the
// lin-fusion epilogue can't poison the non-last layers' codegen (r9 lesson).
// ---------------------------------------------------------------------------

#define R_REL 8

typedef unsigned short ushort_t;
typedef short short8 __attribute__((ext_vector_type(8)));
typedef float f32x4 __attribute__((ext_vector_type(4)));

#define MFMA(a, b, c) __builtin_amdgcn_mfma_f32_16x16x32_bf16(a, b, c, 0, 0, 0)

static __device__ __forceinline__ unsigned short f2bf(float f) {
    unsigned int u = __float_as_uint(f);
    u = (u + 0x7FFF + ((u >> 16) & 1)) >> 16;   // round-to-nearest-even
    return (unsigned short)u;
}
static __device__ __forceinline__ float bf2f(unsigned short h) {
    return __uint_as_float(((unsigned int)h) << 16);
}

// ---- merged weight convert + transpose: 6 arrays, f32 [G][K][64] -> bf16 [G][64][K]
struct WcvtA {
    const float* src[6];
    ushort_t*    dst[6];
    int          end[6];
    int          K[6];
};
__global__ void wcvt6_kernel(WcvtA a, int total)
{
    int i = blockIdx.x * 256 + threadIdx.x;
    if (i >= total) return;
    int s = 0;
    while (i >= a.end[s]) ++s;
    int j = i - (s ? a.end[s - 1] : 0);
    int K = a.K[s];
    int g = j / (K * 64), rem = j % (K * 64), k = rem >> 6, c = rem & 63;
    a.dst[s][(size_t)g * 64 * K + (size_t)c * K + k] = f2bf(a.src[s][j]);
}

// ---- MFMA GEMM (LDS-staged, Ct round-trip for full-line stores).
template<int K, bool AF32>
__global__ __launch_bounds__(256)
void mgemm_kernel(const void* __restrict__ Av, int n,
                  const ushort_t* __restrict__ WT, const ushort_t* __restrict__ RT,
                  const float* __restrict__ bias,
                  ushort_t* __restrict__ H, float* __restrict__ accb)
{
    __shared__ ushort_t As[64][136];
    __shared__ ushort_t Bs[64][136];

    const int row0 = blockIdx.x * 64;
    const int yr = blockIdx.y;
    const ushort_t* Bsrc = (yr < R_REL) ? (WT + (size_t)yr * 64 * K) : RT;

    const int tid = threadIdx.x;
    const int KB = K >> 3;

    for (int i = tid; i < 64 * KB; i += 256) {
        int r = i / KB, k8 = (i % KB) << 3;
        *(uint4*)&Bs[r][k8] = *(const uint4*)&Bsrc[(size_t)r * K + k8];
        if (AF32) {
            const float* Af = (const float*)Av;
            float4 f0 = make_float4(0.f, 0.f, 0.f, 0.f), f1 = f0;
            if (row0 + r < n) {
                f0 = *(const float4*)&Af[(size_t)(row0 + r) * K + k8];
                f1 = *(const float4*)&Af[(size_t)(row0 + r) * K + k8 + 4];
            }
            ushort_t t[8] = {f2bf(f0.x), f2bf(f0.y), f2bf(f0.z), f2bf(f0.w),
                             f2bf(f1.x), f2bf(f1.y), f2bf(f1.z), f2bf(f1.w)};
            *(uint4*)&As[r][k8] = *(const uint4*)t;
        } else {
            const ushort_t* Ab = (const ushort_t*)Av;
            uint4 av = make_uint4(0u, 0u, 0u, 0u);
            if (row0 + r < n) av = *(const uint4*)&Ab[(size_t)(row0 + r) * K + k8];
            *(uint4*)&As[r][k8] = av;
        }
    }
    __syncthreads();

    const int wid  = tid >> 6;
    const int lane = tid & 63;
    const int wr = (wid >> 1) << 5;
    const int wc = (wid & 1) << 5;
    const int fr = lane & 15;
    const int kg = (lane >> 4) << 3;

    f32x4 acc[2][2] = {};
    #pragma unroll
    for (int k0 = 0; k0 < K; k0 += 32) {
        short8 a0 = *(const short8*)&As[wr + fr     ][k0 + kg];
        short8 a1 = *(const short8*)&As[wr + 16 + fr][k0 + kg];
        short8 b0 = *(const short8*)&Bs[wc + fr     ][k0 + kg];
        short8 b1 = *(const short8*)&Bs[wc + 16 + fr][k0 + kg];
        acc[0][0] = MFMA(a0, b0, acc[0][0]);
        acc[0][1] = MFMA(a0, b1, acc[0][1]);
        acc[1][0] = MFMA(a1, b0, acc[1][0]);
        acc[1][1] = MFMA(a1, b1, acc[1][1]);
    }
    __syncthreads();

    float* Ct = (float*)As;            // [64][68] f32
    const int rbase = (lane >> 4) << 2;
    #pragma unroll
    for (int m = 0; m < 2; ++m)
        #pragma unroll
        for (int nn = 0; nn < 2; ++nn)
            #pragma unroll
            for (int j = 0; j < 4; ++j)
                Ct[(wr + m * 16 + rbase + j) * 68 + wc + nn * 16 + fr] = acc[m][nn][j];
    __syncthreads();

    if (yr < R_REL) {
        const int cb = yr << 6;
        for (int i = tid; i < 64 * 8; i += 256) {
            int r = i >> 3, c8 = (i & 7) << 3;
            if (row0 + r < n) {
                ushort_t t[8];
                #pragma unroll
                for (int j = 0; j < 8; ++j) t[j] = f2bf(Ct[r * 68 + c8 + j]);
                *(uint4*)&H[(size_t)(row0 + r) * 512 + cb + c8] = *(const uint4*)t;
            }
        }
    } else {
        for (int i = tid; i < 64 * 16; i += 256) {
            int r = i >> 4, c4 = (i & 15) << 2;
            if (row0 + r < n) {
                float4 o;
                o.x = Ct[r * 68 + c4 + 0] + bias[c4 + 0];
                o.y = Ct[r * 68 + c4 + 1] + bias[c4 + 1];
                o.z = Ct[r * 68 + c4 + 2] + bias[c4 + 2];
                o.w = Ct[r * 68 + c4 + 3] + bias[c4 + 3];
                *(float4*)&accb[(size_t)(row0 + r) * 64 + c4] = o;
            }
        }
    }
}

// ---- CSR build -------------------------------------------------------------
__global__ void count_kernel(const int* __restrict__ ei, const int* __restrict__ et,
                             int* __restrict__ cnt, int E)
{
    int e = blockIdx.x * 256 + threadIdx.x;
    if (e < E) atomicAdd(&cnt[(size_t)ei[E + e] * R_REL + et[e]], 1);
}

__global__ void invdeg_scan_kernel(float* __restrict__ inv, int* __restrict__ deg,
                                   int* __restrict__ offs, int* __restrict__ partials,
                                   int N)
{
    __shared__ int sm[256];
    int i = blockIdx.x * 256 + threadIdx.x;
    int tot = 0;
    if (i < N) {
        const int* c = (const int*)inv;
        float out[R_REL];
        #pragma unroll
        for (int r = 0; r < R_REL; ++r) {
            int cc = c[(size_t)i * R_REL + r];
            tot += cc;
            out[r] = 1.0f / (float)(cc > 1 ? cc : 1);
        }
        #pragma unroll
        for (int r = 0; r < R_REL; ++r) inv[(size_t)i * R_REL + r] = out[r];
        deg[i] = tot;
    }
    sm[threadIdx.x] = tot;
    __syncthreads();
    for (int off = 1; off < 256; off <<= 1) {
        int t = (threadIdx.x >= off) ? sm[threadIdx.x - off] : 0;
        __syncthreads();
        sm[threadIdx.x] += t;
        __syncthreads();
    }
    if (i < N) offs[i] = sm[threadIdx.x] - tot;
    if (threadIdx.x == 255) partials[blockIdx.x] = sm[255];
}

__global__ void scan2_kernel(int* __restrict__ partials, int P)
{
    __shared__ int sm[256];
    __shared__ int carry;
    if (threadIdx.x == 0) carry = 0;
    __syncthreads();
    for (int base = 0; base < P; base += 256) {
        int i = base + threadIdx.x;
        int c = (i < P) ? partials[i] : 0;
        sm[threadIdx.x] = c;
        __syncthreads();
        for (int off = 1; off < 256; off <<= 1) {
            int t = (threadIdx.x >= off) ? sm[threadIdx.x - off] : 0;
            __syncthreads();
            sm[threadIdx.x] += t;
            __syncthreads();
        }
        int incl = sm[threadIdx.x];
        int cold = carry;
        if (i < P) partials[i] = incl - c + cold;
        __syncthreads();
        if (threadIdx.x == 0) carry = cold + sm[255];
        __syncthreads();
    }
}

__global__ void scan3_kernel(int* __restrict__ offs, const int* __restrict__ partials, int N)
{
    int i = blockIdx.x * 256 + threadIdx.x;
    if (i < N) offs[i] += partials[blockIdx.x];
}

// scatter: ep[pos] = {src*512 + r*64, bits(1/cnt(dst,rel))}
__global__ void fill3_kernel(const int* __restrict__ ei, const int* __restrict__ et,
                             const int* __restrict__ offs, int* __restrict__ cursor,
                             const float* __restrict__ inv,
                             int2* __restrict__ ep, int E)
{
    int e = blockIdx.x * 256 + threadIdx.x;
    if (e >= E) return;
    int d = ei[E + e];
    int r = et[e];
    int pos = offs[d] + atomicAdd(&cursor[d], 1);
    ep[pos] = make_int2(ei[e] * 512 + r * 64,
                        __float_as_int(inv[(size_t)d * R_REL + r]));
}

// ---- one wave per dst. All 64 lanes prefetch edge records coalesced
// (ep[n0+lane]); per 8-edge step, offsets/weights come from __shfl broadcast
// (register), so H gathers pipeline without the ep->H pointer chase.
// Padded lanes hold {0,0}: weight 0 annihilates phantom contributions.
template<bool LAST>
__global__ __launch_bounds__(256)
void agg6_kernel(const int2* __restrict__ ep,
                 const int* __restrict__ offs, const int* __restrict__ deg,
                 const ushort_t* __restrict__ H, const float* __restrict__ accb,
                 const float* __restrict__ g, const float* __restrict__ b,
                 const float* __restrict__ rm, const float* __restrict__ rv,
                 ushort_t* __restrict__ xout,
                 const float* __restrict__ Wl, const float* __restrict__ bl,
                 float* __restrict__ out, int N)
{
    const int lane = threadIdx.x & 63;
    const int d = (blockIdx.x * 256 + threadIdx.x) >> 6;
    if (d >= N) return;

    const int sub = lane >> 4;
    const int fl  = lane & 15;
    const int n0 = offs[d];
    const int dg = deg[d];

    float s0 = 0.f, s1 = 0.f, s2 = 0.f, s3 = 0.f;

    for (int c0 = 0; c0 < dg; c0 += 64) {
        const int cnt = dg - c0 < 64 ? dg - c0 : 64;
        int2 my = (lane < cnt) ? ep[n0 + c0 + lane] : make_int2(0, 0);

        for (int e = 0; e < cnt; e += 8) {
            int oA = __shfl(my.x, e + sub);
            int wAi = __shfl(my.y, e + sub);
            int oB = __shfl(my.x, e + 4 + sub);
            int wBi = __shfl(my.y, e + 4 + sub);
            uint2 hA = *(const uint2*)&H[(size_t)oA + (fl << 2)];
            uint2 hB = *(const uint2*)&H[(size_t)oB + (fl << 2)];
            float wA = __int_as_float(wAi);
            float wB = __int_as_float(wBi);
            s0 += bf2f((ushort_t)(hA.x & 0xFFFF)) * wA + bf2f((ushort_t)(hB.x & 0xFFFF)) * wB;
            s1 += bf2f((ushort_t)(hA.x >> 16))    * wA + bf2f((ushort_t)(hB.x >> 16))    * wB;
            s2 += bf2f((ushort_t)(hA.y & 0xFFFF)) * wA + bf2f((ushort_t)(hB.y & 0xFFFF)) * wB;
            s3 += bf2f((ushort_t)(hA.y >> 16))    * wA + bf2f((ushort_t)(hB.y >> 16))    * wB;
        }
    }

    s0 += __shfl_xor(s0, 16); s1 += __shfl_xor(s1, 16);
    s2 += __shfl_xor(s2, 16); s3 += __shfl_xor(s3, 16);
    s0 += __shfl_xor(s0, 32); s1 += __shfl_xor(s1, 32);
    s2 += __shfl_xor(s2, 32); s3 += __shfl_xor(s3, 32);

    if (sub == 0) {
        const int c4 = fl << 2;
        float4 aq = *(const float4*)&accb[(size_t)d * 64 + c4];
        float4 gm = *(const float4*)&g[c4];
        float4 bt = *(const float4*)&b[c4];
        float4 mu = *(const float4*)&rm[c4];
        float4 vr = *(const float4*)&rv[c4];
        float t0 = aq.x + s0, t1 = aq.y + s1, t2 = aq.z + s2, t3 = aq.w + s3;
        t0 = t0 > 0.f ? t0 : 0.f;  t1 = t1 > 0.f ? t1 : 0.f;
        t2 = t2 > 0.f ? t2 : 0.f;  t3 = t3 > 0.f ? t3 : 0.f;
        t0 = (t0 - mu.x) * rsqrtf(vr.x + 1e-5f) * gm.x + bt.x;
        t1 = (t1 - mu.y) * rsqrtf(vr.y + 1e-5f) * gm.y + bt.y;
        t2 = (t2 - mu.z) * rsqrtf(vr.z + 1e-5f) * gm.z + bt.z;
        t3 = (t3 - mu.w) * rsqrtf(vr.w + 1e-5f) * gm.w + bt.w;

        if (!LAST) {
            ushort_t o[4] = {f2bf(t0), f2bf(t1), f2bf(t2), f2bf(t3)};
            *(uint2*)&xout[(size_t)d * 64 + c4] = *(const uint2*)o;
        } else {
            f32x4 p[4] = {};
            float tt[4] = {t0, t1, t2, t3};
            #pragma unroll
            for (int i = 0; i < 4; ++i) {
                const float* wrow = &Wl[(size_t)(c4 + i) * 16];
                #pragma unroll
                for (int q = 0; q < 4; ++q)
                    p[q] += tt[i] * (*(const f32x4*)&wrow[q * 4]);
            }
            #pragma unroll
            for (int m = 1; m < 16; m <<= 1) {
                #pragma unroll
                for (int q = 0; q < 4; ++q) {
                    p[q][0] += __shfl_xor(p[q][0], m);
                    p[q][1] += __shfl_xor(p[q][1], m);
                    p[q][2] += __shfl_xor(p[q][2], m);
                    p[q][3] += __shfl_xor(p[q][3], m);
                }
            }
            if (fl == 0) {
                #pragma unroll
                for (int q = 0; q < 4; ++q) {
                    f32x4 bv = *(const f32x4*)&bl[q * 4];
                    f32x4 o = p[q] + bv;
                    *(f32x4*)&out[(size_t)d * 16 + q * 4] = o;
                }
            }
        }
    }
}

extern "C" void kernel_launch(void* const* d_in, const int* in_sizes, int n_in,
                              void* d_out, int out_size, void* d_ws, size_t ws_size,
                              hipStream_t stream)
{
    const float* x  = (const float*)d_in[0];
    const int*   ei = (const int*)d_in[1];
    const int*   et = (const int*)d_in[2];
    const float* W[3]    = {(const float*)d_in[3], (const float*)d_in[6], (const float*)d_in[9]};
    const float* root[3] = {(const float*)d_in[4], (const float*)d_in[7], (const float*)d_in[10]};
    const float* bias[3] = {(const float*)d_in[5], (const float*)d_in[8], (const float*)d_in[11]};
    const float* gamma[3] = {(const float*)d_in[12], (const float*)d_in[16], (const float*)d_in[20]};
    const float* beta[3]  = {(const float*)d_in[13], (const float*)d_in[17], (const float*)d_in[21]};
    const float* rm[3]    = {(const float*)d_in[14], (const float*)d_in[18], (const float*)d_in[22]};
    const float* rv[3]    = {(const float*)d_in[15], (const float*)d_in[19], (const float*)d_in[23]};
    const float* Wl = (const float*)d_in[24];
    const float* bl = (const float*)d_in[25];

    const int N = in_sizes[0] / 128;
    const int E = in_sizes[2];
    const int K1 = 128;

    // ---- workspace layout (all 16B aligned) ----
    char* p = (char*)d_ws;
    float*   inv  = (float*)p;    p += (size_t)N * R_REL * 4;
    ushort_t* Hbuf = (ushort_t*)p; p += (size_t)N * 512 * 2;
    float*   accb = (float*)p;    p += (size_t)N * 64 * 4;
    ushort_t* xb  = (ushort_t*)p; p += (size_t)N * 64 * 2;
    ushort_t* wt0 = (ushort_t*)p; p += (size_t)R_REL * 64 * K1 * 2;
    ushort_t* wt1 = (ushort_t*)p; p += (size_t)R_REL * 64 * 64 * 2;
    ushort_t* wt2 = (ushort_t*)p; p += (size_t)R_REL * 64 * 64 * 2;
    ushort_t* rt0 = (ushort_t*)p; p += (size_t)64 * K1 * 2;
    ushort_t* rt1 = (ushort_t*)p; p += (size_t)64 * 64 * 2;
    ushort_t* rt2 = (ushort_t*)p; p += (size_t)64 * 64 * 2;
    int*   offs    = (int*)p;     p += (size_t)N * 4;
    int*   deg     = (int*)p;     p += (size_t)N * 4;
    int*   cursor  = (int*)p;     p += (size_t)N * 4;
    int2*  ep      = (int2*)p;    p += (size_t)E * 8;
    int*   partials = (int*)p;

    const ushort_t* wt[3] = {wt0, wt1, wt2};
    const ushort_t* rt[3] = {rt0, rt1, rt2};

    const int gxN = (N + 255) / 256;

    // ---- weight conversion (one kernel) ----
    {
        WcvtA a;
        a.src[0] = W[0];   a.dst[0] = wt0; a.K[0] = K1;
        a.src[1] = W[1];   a.dst[1] = wt1; a.K[1] = 64;
        a.src[2] = W[2];   a.dst[2] = wt2; a.K[2] = 64;
        a.src[3] = root[0]; a.dst[3] = rt0; a.K[3] = K1;
        a.src[4] = root[1]; a.dst[4] = rt1; a.K[4] = 64;
        a.src[5] = root[2]; a.dst[5] = rt2; a.K[5] = 64;
        int sizes[6] = {R_REL * K1 * 64, R_REL * 64 * 64, R_REL * 64 * 64,
                        K1 * 64, 64 * 64, 64 * 64};
        int acc = 0;
        for (int i = 0; i < 6; ++i) { acc += sizes[i]; a.end[i] = acc; }
        wcvt6_kernel<<<(acc + 255) / 256, 256, 0, stream>>>(a, acc);
    }

    // ---- CSR build ----
    hipMemsetAsync(inv, 0, (size_t)N * R_REL * 4, stream);
    hipMemsetAsync(cursor, 0, (size_t)N * 4, stream);
    count_kernel<<<(E + 255) / 256, 256, 0, stream>>>(ei, et, (int*)inv, E);
    invdeg_scan_kernel<<<gxN, 256, 0, stream>>>(inv, deg, offs, partials, N);
    scan2_kernel<<<1, 256, 0, stream>>>(partials, gxN);
    scan3_kernel<<<gxN, 256, 0, stream>>>(offs, partials, N);
    fill3_kernel<<<(E + 255) / 256, 256, 0, stream>>>(ei, et, offs, cursor, inv, ep, E);

    // ---- 3 RGCN layers ----
    const int gx = (N + 63) / 64;
    const int gagg = (N * 64 + 255) / 256;
    const ushort_t* cur = nullptr;
    for (int layer = 0; layer < 3; ++layer) {
        if (layer == 0)
            mgemm_kernel<128, true><<<dim3(gx, R_REL + 1), 256, 0, stream>>>(
                (const void*)x, N, wt[0], rt[0], bias[0], Hbuf, accb);
        else
            mgemm_kernel<64, false><<<dim3(gx, R_REL + 1), 256, 0, stream>>>(
                (const void*)cur, N, wt[layer], rt[layer], bias[layer], Hbuf, accb);
        if (layer < 2)
            agg6_kernel<false><<<gagg, 256, 0, stream>>>(
                ep, offs, deg, Hbuf, accb,
                gamma[layer], beta[layer], rm[layer], rv[layer],
                xb, Wl, bl, (float*)d_out, N);
        else
            agg6_kernel<true><<<gagg, 256, 0, stream>>>(
                ep, offs, deg, Hbuf, accb,
                gamma[layer], beta[layer], rm[layer], rv[layer],
                xb, Wl, bl, (float*)d_out, N);
        cur = xb;
    }
}

// Round 11
// 401.316 us; speedup vs baseline: 1.0640x; 1.0117x over previous
//
#include <hip/hip_runtime.h>

// ---------------------------------------------------------------------------
// HeteroRGCN: 3x (RGCNConv mean-per-relation + ReLU + BN(eval)) + Linear
// Round 11: agg with 16-edges-in-flight (4 independent gathers/iter);
// mgemm stages A once per block and loops 3 output tiles (A-refetch 9x->3x).
// ---------------------------------------------------------------------------

#define R_REL 8

typedef unsigned short ushort_t;
typedef short short8 __attribute__((ext_vector_type(8)));
typedef float f32x4 __attribute__((ext_vector_type(4)));

#define MFMA(a, b, c) __builtin_amdgcn_mfma_f32_16x16x32_bf16(a, b, c, 0, 0, 0)

static __device__ __forceinline__ unsigned short f2bf(float f) {
    unsigned int u = __float_as_uint(f);
    u = (u + 0x7FFF + ((u >> 16) & 1)) >> 16;   // round-to-nearest-even
    return (unsigned short)u;
}
static __device__ __forceinline__ float bf2f(unsigned short h) {
    return __uint_as_float(((unsigned int)h) << 16);
}

// ---- merged weight convert + transpose: 6 arrays, f32 [G][K][64] -> bf16 [G][64][K]
struct WcvtA {
    const float* src[6];
    ushort_t*    dst[6];
    int          end[6];
    int          K[6];
};
__global__ void wcvt6_kernel(WcvtA a, int total)
{
    int i = blockIdx.x * 256 + threadIdx.x;
    if (i >= total) return;
    int s = 0;
    while (i >= a.end[s]) ++s;
    int j = i - (s ? a.end[s - 1] : 0);
    int K = a.K[s];
    int g = j / (K * 64), rem = j % (K * 64), k = rem >> 6, c = rem & 63;
    a.dst[s][(size_t)g * 64 * K + (size_t)c * K + k] = f2bf(a.src[s][j]);
}

// ---- MFMA GEMM, A staged once per block, 3 output tiles per block.
// blockIdx.y = yr3 in {0,1,2}: handles r = 3*yr3 .. 3*yr3+2 (r==8 -> root).
template<int K, bool AF32>
__global__ __launch_bounds__(256)
void mgemm3_kernel(const void* __restrict__ Av, int n,
                   const ushort_t* __restrict__ WT, const ushort_t* __restrict__ RT,
                   const float* __restrict__ bias,
                   ushort_t* __restrict__ H, float* __restrict__ accb)
{
    __shared__ ushort_t As[64][K + 8];
    __shared__ ushort_t Bs[64][K + 8];
    __shared__ float    Ct[64][68];

    const int row0 = blockIdx.x * 64;
    const int tid = threadIdx.x;
    const int KB = K >> 3;

    // stage A once
    for (int i = tid; i < 64 * KB; i += 256) {
        int r = i / KB, k8 = (i % KB) << 3;
        if (AF32) {
            const float* Af = (const float*)Av;
            float4 f0 = make_float4(0.f, 0.f, 0.f, 0.f), f1 = f0;
            if (row0 + r < n) {
                f0 = *(const float4*)&Af[(size_t)(row0 + r) * K + k8];
                f1 = *(const float4*)&Af[(size_t)(row0 + r) * K + k8 + 4];
            }
            ushort_t t[8] = {f2bf(f0.x), f2bf(f0.y), f2bf(f0.z), f2bf(f0.w),
                             f2bf(f1.x), f2bf(f1.y), f2bf(f1.z), f2bf(f1.w)};
            *(uint4*)&As[r][k8] = *(const uint4*)t;
        } else {
            const ushort_t* Ab = (const ushort_t*)Av;
            uint4 av = make_uint4(0u, 0u, 0u, 0u);
            if (row0 + r < n) av = *(const uint4*)&Ab[(size_t)(row0 + r) * K + k8];
            *(uint4*)&As[r][k8] = av;
        }
    }

    const int wid  = tid >> 6;
    const int lane = tid & 63;
    const int wr = (wid >> 1) << 5;
    const int wc = (wid & 1) << 5;
    const int fr = lane & 15;
    const int kg = (lane >> 4) << 3;
    const int rbase = (lane >> 4) << 2;

    for (int j = 0; j < 3; ++j) {
        const int r = blockIdx.y * 3 + j;
        const ushort_t* Bsrc = (r < R_REL) ? (WT + (size_t)r * 64 * K) : RT;

        __syncthreads();   // guards Bs (prev MFMA reads) & Ct (prev stores)
        for (int i = tid; i < 64 * KB; i += 256) {
            int rr = i / KB, k8 = (i % KB) << 3;
            *(uint4*)&Bs[rr][k8] = *(const uint4*)&Bsrc[(size_t)rr * K + k8];
        }
        __syncthreads();

        f32x4 acc[2][2] = {};
        #pragma unroll
        for (int k0 = 0; k0 < K; k0 += 32) {
            short8 a0 = *(const short8*)&As[wr + fr     ][k0 + kg];
            short8 a1 = *(const short8*)&As[wr + 16 + fr][k0 + kg];
            short8 b0 = *(const short8*)&Bs[wc + fr     ][k0 + kg];
            short8 b1 = *(const short8*)&Bs[wc + 16 + fr][k0 + kg];
            acc[0][0] = MFMA(a0, b0, acc[0][0]);
            acc[0][1] = MFMA(a0, b1, acc[0][1]);
            acc[1][0] = MFMA(a1, b0, acc[1][0]);
            acc[1][1] = MFMA(a1, b1, acc[1][1]);
        }
        __syncthreads();   // MFMA reads done before Ct write (Ct separate, but
                           // also orders vs prev j's Ct readers)

        #pragma unroll
        for (int m = 0; m < 2; ++m)
            #pragma unroll
            for (int nn = 0; nn < 2; ++nn)
                #pragma unroll
                for (int q = 0; q < 4; ++q)
                    Ct[wr + m * 16 + rbase + q][wc + nn * 16 + fr] = acc[m][nn][q];
        __syncthreads();

        if (r < R_REL) {
            const int cb = r << 6;
            for (int i = tid; i < 64 * 8; i += 256) {
                int rr = i >> 3, c8 = (i & 7) << 3;
                if (row0 + rr < n) {
                    ushort_t t[8];
                    #pragma unroll
                    for (int q = 0; q < 8; ++q) t[q] = f2bf(Ct[rr][c8 + q]);
                    *(uint4*)&H[(size_t)(row0 + rr) * 512 + cb + c8] = *(const uint4*)t;
                }
            }
        } else {
            for (int i = tid; i < 64 * 16; i += 256) {
                int rr = i >> 4, c4 = (i & 15) << 2;
                if (row0 + rr < n) {
                    float4 o;
                    o.x = Ct[rr][c4 + 0] + bias[c4 + 0];
                    o.y = Ct[rr][c4 + 1] + bias[c4 + 1];
                    o.z = Ct[rr][c4 + 2] + bias[c4 + 2];
                    o.w = Ct[rr][c4 + 3] + bias[c4 + 3];
                    *(float4*)&accb[(size_t)(row0 + rr) * 64 + c4] = o;
                }
            }
        }
    }
}

// ---- CSR build -------------------------------------------------------------
__global__ void count_kernel(const int* __restrict__ ei, const int* __restrict__ et,
                             int* __restrict__ cnt, int E)
{
    int e = blockIdx.x * 256 + threadIdx.x;
    if (e < E) atomicAdd(&cnt[(size_t)ei[E + e] * R_REL + et[e]], 1);
}

__global__ void invdeg_scan_kernel(float* __restrict__ inv, int* __restrict__ deg,
                                   int* __restrict__ offs, int* __restrict__ partials,
                                   int N)
{
    __shared__ int sm[256];
    int i = blockIdx.x * 256 + threadIdx.x;
    int tot = 0;
    if (i < N) {
        const int* c = (const int*)inv;
        float out[R_REL];
        #pragma unroll
        for (int r = 0; r < R_REL; ++r) {
            int cc = c[(size_t)i * R_REL + r];
            tot += cc;
            out[r] = 1.0f / (float)(cc > 1 ? cc : 1);
        }
        #pragma unroll
        for (int r = 0; r < R_REL; ++r) inv[(size_t)i * R_REL + r] = out[r];
        deg[i] = tot;
    }
    sm[threadIdx.x] = tot;
    __syncthreads();
    for (int off = 1; off < 256; off <<= 1) {
        int t = (threadIdx.x >= off) ? sm[threadIdx.x - off] : 0;
        __syncthreads();
        sm[threadIdx.x] += t;
        __syncthreads();
    }
    if (i < N) offs[i] = sm[threadIdx.x] - tot;
    if (threadIdx.x == 255) partials[blockIdx.x] = sm[255];
}

__global__ void scan2_kernel(int* __restrict__ partials, int P)
{
    __shared__ int sm[256];
    __shared__ int carry;
    if (threadIdx.x == 0) carry = 0;
    __syncthreads();
    for (int base = 0; base < P; base += 256) {
        int i = base + threadIdx.x;
        int c = (i < P) ? partials[i] : 0;
        sm[threadIdx.x] = c;
        __syncthreads();
        for (int off = 1; off < 256; off <<= 1) {
            int t = (threadIdx.x >= off) ? sm[threadIdx.x - off] : 0;
            __syncthreads();
            sm[threadIdx.x] += t;
            __syncthreads();
        }
        int incl = sm[threadIdx.x];
        int cold = carry;
        if (i < P) partials[i] = incl - c + cold;
        __syncthreads();
        if (threadIdx.x == 0) carry = cold + sm[255];
        __syncthreads();
    }
}

__global__ void scan3_kernel(int* __restrict__ offs, const int* __restrict__ partials, int N)
{
    int i = blockIdx.x * 256 + threadIdx.x;
    if (i < N) offs[i] += partials[blockIdx.x];
}

// scatter: ep[pos] = {src*512 + r*64, bits(1/cnt(dst,rel))}
__global__ void fill3_kernel(const int* __restrict__ ei, const int* __restrict__ et,
                             const int* __restrict__ offs, int* __restrict__ cursor,
                             const float* __restrict__ inv,
                             int2* __restrict__ ep, int E)
{
    int e = blockIdx.x * 256 + threadIdx.x;
    if (e >= E) return;
    int d = ei[E + e];
    int r = et[e];
    int pos = offs[d] + atomicAdd(&cursor[d], 1);
    ep[pos] = make_int2(ei[e] * 512 + r * 64,
                        __float_as_int(inv[(size_t)d * R_REL + r]));
}

// ---- one wave per dst; 64 records prefetched coalesced; 16 edges in flight
// per inner iteration (4 independent uint2 gathers). Padded records {0,0}
// contribute 0 (weight 0), making all windows branch-free.
template<bool LAST>
__global__ __launch_bounds__(256)
void agg7_kernel(const int2* __restrict__ ep,
                 const int* __restrict__ offs, const int* __restrict__ deg,
                 const ushort_t* __restrict__ H, const float* __restrict__ accb,
                 const float* __restrict__ g, const float* __restrict__ b,
                 const float* __restrict__ rm, const float* __restrict__ rv,
                 ushort_t* __restrict__ xout,
                 const float* __restrict__ Wl, const float* __restrict__ bl,
                 float* __restrict__ out, int N)
{
    const int lane = threadIdx.x & 63;
    const int d = (blockIdx.x * 256 + threadIdx.x) >> 6;
    if (d >= N) return;

    const int sub = lane >> 4;
    const int fl  = lane & 15;
    const int n0 = offs[d];
    const int dg = deg[d];

    float s0 = 0.f, s1 = 0.f, s2 = 0.f, s3 = 0.f;

    for (int c0 = 0; c0 < dg; c0 += 64) {
        const int cnt = dg - c0 < 64 ? dg - c0 : 64;
        int2 my = (lane < cnt) ? ep[n0 + c0 + lane] : make_int2(0, 0);

        for (int e = 0; e < cnt; e += 16) {
            int o0 = __shfl(my.x, e + sub),      w0i = __shfl(my.y, e + sub);
            int o1 = __shfl(my.x, e + 4 + sub),  w1i = __shfl(my.y, e + 4 + sub);
            int o2 = __shfl(my.x, e + 8 + sub),  w2i = __shfl(my.y, e + 8 + sub);
            int o3 = __shfl(my.x, e + 12 + sub), w3i = __shfl(my.y, e + 12 + sub);
            uint2 h0 = *(const uint2*)&H[(size_t)o0 + (fl << 2)];
            uint2 h1 = *(const uint2*)&H[(size_t)o1 + (fl << 2)];
            uint2 h2 = *(const uint2*)&H[(size_t)o2 + (fl << 2)];
            uint2 h3 = *(const uint2*)&H[(size_t)o3 + (fl << 2)];
            float w0 = __int_as_float(w0i), w1 = __int_as_float(w1i);
            float w2 = __int_as_float(w2i), w3 = __int_as_float(w3i);
            s0 += bf2f((ushort_t)(h0.x & 0xFFFF)) * w0 + bf2f((ushort_t)(h1.x & 0xFFFF)) * w1
                + bf2f((ushort_t)(h2.x & 0xFFFF)) * w2 + bf2f((ushort_t)(h3.x & 0xFFFF)) * w3;
            s1 += bf2f((ushort_t)(h0.x >> 16))    * w0 + bf2f((ushort_t)(h1.x >> 16))    * w1
                + bf2f((ushort_t)(h2.x >> 16))    * w2 + bf2f((ushort_t)(h3.x >> 16))    * w3;
            s2 += bf2f((ushort_t)(h0.y & 0xFFFF)) * w0 + bf2f((ushort_t)(h1.y & 0xFFFF)) * w1
                + bf2f((ushort_t)(h2.y & 0xFFFF)) * w2 + bf2f((ushort_t)(h3.y & 0xFFFF)) * w3;
            s3 += bf2f((ushort_t)(h0.y >> 16))    * w0 + bf2f((ushort_t)(h1.y >> 16))    * w1
                + bf2f((ushort_t)(h2.y >> 16))    * w2 + bf2f((ushort_t)(h3.y >> 16))    * w3;
        }
    }

    s0 += __shfl_xor(s0, 16); s1 += __shfl_xor(s1, 16);
    s2 += __shfl_xor(s2, 16); s3 += __shfl_xor(s3, 16);
    s0 += __shfl_xor(s0, 32); s1 += __shfl_xor(s1, 32);
    s2 += __shfl_xor(s2, 32); s3 += __shfl_xor(s3, 32);

    if (sub == 0) {
        const int c4 = fl << 2;
        float4 aq = *(const float4*)&accb[(size_t)d * 64 + c4];
        float4 gm = *(const float4*)&g[c4];
        float4 bt = *(const float4*)&b[c4];
        float4 mu = *(const float4*)&rm[c4];
        float4 vr = *(const float4*)&rv[c4];
        float t0 = aq.x + s0, t1 = aq.y + s1, t2 = aq.z + s2, t3 = aq.w + s3;
        t0 = t0 > 0.f ? t0 : 0.f;  t1 = t1 > 0.f ? t1 : 0.f;
        t2 = t2 > 0.f ? t2 : 0.f;  t3 = t3 > 0.f ? t3 : 0.f;
        t0 = (t0 - mu.x) * rsqrtf(vr.x + 1e-5f) * gm.x + bt.x;
        t1 = (t1 - mu.y) * rsqrtf(vr.y + 1e-5f) * gm.y + bt.y;
        t2 = (t2 - mu.z) * rsqrtf(vr.z + 1e-5f) * gm.z + bt.z;
        t3 = (t3 - mu.w) * rsqrtf(vr.w + 1e-5f) * gm.w + bt.w;

        if (!LAST) {
            ushort_t o[4] = {f2bf(t0), f2bf(t1), f2bf(t2), f2bf(t3)};
            *(uint2*)&xout[(size_t)d * 64 + c4] = *(const uint2*)o;
        } else {
            f32x4 p[4] = {};
            float tt[4] = {t0, t1, t2, t3};
            #pragma unroll
            for (int i = 0; i < 4; ++i) {
                const float* wrow = &Wl[(size_t)(c4 + i) * 16];
                #pragma unroll
                for (int q = 0; q < 4; ++q)
                    p[q] += tt[i] * (*(const f32x4*)&wrow[q * 4]);
            }
            #pragma unroll
            for (int m = 1; m < 16; m <<= 1) {
                #pragma unroll
                for (int q = 0; q < 4; ++q) {
                    p[q][0] += __shfl_xor(p[q][0], m);
                    p[q][1] += __shfl_xor(p[q][1], m);
                    p[q][2] += __shfl_xor(p[q][2], m);
                    p[q][3] += __shfl_xor(p[q][3], m);
                }
            }
            if (fl == 0) {
                #pragma unroll
                for (int q = 0; q < 4; ++q) {
                    f32x4 bv = *(const f32x4*)&bl[q * 4];
                    f32x4 o = p[q] + bv;
                    *(f32x4*)&out[(size_t)d * 16 + q * 4] = o;
                }
            }
        }
    }
}

extern "C" void kernel_launch(void* const* d_in, const int* in_sizes, int n_in,
                              void* d_out, int out_size, void* d_ws, size_t ws_size,
                              hipStream_t stream)
{
    const float* x  = (const float*)d_in[0];
    const int*   ei = (const int*)d_in[1];
    const int*   et = (const int*)d_in[2];
    const float* W[3]    = {(const float*)d_in[3], (const float*)d_in[6], (const float*)d_in[9]};
    const float* root[3] = {(const float*)d_in[4], (const float*)d_in[7], (const float*)d_in[10]};
    const float* bias[3] = {(const float*)d_in[5], (const float*)d_in[8], (const float*)d_in[11]};
    const float* gamma[3] = {(const float*)d_in[12], (const float*)d_in[16], (const float*)d_in[20]};
    const float* beta[3]  = {(const float*)d_in[13], (const float*)d_in[17], (const float*)d_in[21]};
    const float* rm[3]    = {(const float*)d_in[14], (const float*)d_in[18], (const float*)d_in[22]};
    const float* rv[3]    = {(const float*)d_in[15], (const float*)d_in[19], (const float*)d_in[23]};
    const float* Wl = (const float*)d_in[24];
    const float* bl = (const float*)d_in[25];

    const int N = in_sizes[0] / 128;
    const int E = in_sizes[2];
    const int K1 = 128;

    // ---- workspace layout (all 16B aligned) ----
    char* p = (char*)d_ws;
    float*   inv  = (float*)p;    p += (size_t)N * R_REL * 4;
    ushort_t* Hbuf = (ushort_t*)p; p += (size_t)N * 512 * 2;
    float*   accb = (float*)p;    p += (size_t)N * 64 * 4;
    ushort_t* xb  = (ushort_t*)p; p += (size_t)N * 64 * 2;
    ushort_t* wt0 = (ushort_t*)p; p += (size_t)R_REL * 64 * K1 * 2;
    ushort_t* wt1 = (ushort_t*)p; p += (size_t)R_REL * 64 * 64 * 2;
    ushort_t* wt2 = (ushort_t*)p; p += (size_t)R_REL * 64 * 64 * 2;
    ushort_t* rt0 = (ushort_t*)p; p += (size_t)64 * K1 * 2;
    ushort_t* rt1 = (ushort_t*)p; p += (size_t)64 * 64 * 2;
    ushort_t* rt2 = (ushort_t*)p; p += (size_t)64 * 64 * 2;
    int*   offs    = (int*)p;     p += (size_t)N * 4;
    int*   deg     = (int*)p;     p += (size_t)N * 4;
    int*   cursor  = (int*)p;     p += (size_t)N * 4;
    int2*  ep      = (int2*)p;    p += (size_t)E * 8;
    int*   partials = (int*)p;

    const ushort_t* wt[3] = {wt0, wt1, wt2};
    const ushort_t* rt[3] = {rt0, rt1, rt2};

    const int gxN = (N + 255) / 256;

    // ---- weight conversion (one kernel) ----
    {
        WcvtA a;
        a.src[0] = W[0];   a.dst[0] = wt0; a.K[0] = K1;
        a.src[1] = W[1];   a.dst[1] = wt1; a.K[1] = 64;
        a.src[2] = W[2];   a.dst[2] = wt2; a.K[2] = 64;
        a.src[3] = root[0]; a.dst[3] = rt0; a.K[3] = K1;
        a.src[4] = root[1]; a.dst[4] = rt1; a.K[4] = 64;
        a.src[5] = root[2]; a.dst[5] = rt2; a.K[5] = 64;
        int sizes[6] = {R_REL * K1 * 64, R_REL * 64 * 64, R_REL * 64 * 64,
                        K1 * 64, 64 * 64, 64 * 64};
        int acc = 0;
        for (int i = 0; i < 6; ++i) { acc += sizes[i]; a.end[i] = acc; }
        wcvt6_kernel<<<(acc + 255) / 256, 256, 0, stream>>>(a, acc);
    }

    // ---- CSR build ----
    hipMemsetAsync(inv, 0, (size_t)N * R_REL * 4, stream);
    hipMemsetAsync(cursor, 0, (size_t)N * 4, stream);
    count_kernel<<<(E + 255) / 256, 256, 0, stream>>>(ei, et, (int*)inv, E);
    invdeg_scan_kernel<<<gxN, 256, 0, stream>>>(inv, deg, offs, partials, N);
    scan2_kernel<<<1, 256, 0, stream>>>(partials, gxN);
    scan3_kernel<<<gxN, 256, 0, stream>>>(offs, partials, N);
    fill3_kernel<<<(E + 255) / 256, 256, 0, stream>>>(ei, et, offs, cursor, inv, ep, E);

    // ---- 3 RGCN layers ----
    const int gx = (N + 63) / 64;
    const int gagg = (N * 64 + 255) / 256;
    const ushort_t* cur = nullptr;
    for (int layer = 0; layer < 3; ++layer) {
        if (layer == 0)
            mgemm3_kernel<128, true><<<dim3(gx, 3), 256, 0, stream>>>(
                (const void*)x, N, wt[0], rt[0], bias[0], Hbuf, accb);
        else
            mgemm3_kernel<64, false><<<dim3(gx, 3), 256, 0, stream>>>(
                (const void*)cur, N, wt[layer], rt[layer], bias[layer], Hbuf, accb);
        if (layer < 2)
            agg7_kernel<false><<<gagg, 256, 0, stream>>>(
                ep, offs, deg, Hbuf, accb,
                gamma[layer], beta[layer], rm[layer], rv[layer],
                xb, Wl, bl, (float*)d_out, N);
        else
            agg7_kernel<true><<<gagg, 256, 0, stream>>>(
                ep, offs, deg, Hbuf, accb,
                gamma[layer], beta[layer], rm[layer], rv[layer],
                xb, Wl, bl, (float*)d_out, N);
        cur = xb;
    }
}

// Round 12
// 378.459 us; speedup vs baseline: 1.1283x; 1.0604x over previous
//
#include <hip/hip_runtime.h>

// ---------------------------------------------------------------------------
// HeteroRGCN: 3x (RGCNConv mean-per-relation + ReLU + BN(eval)) + Linear
// Round 12: restore r7's exact agg3 (lean epilogue, no lin fusion, ~45us
// historically) + separate lin_kernel; keep mgemm3 (A staged once, 3 tiles),
// merged wcvt6, fused invdeg_scan, f32-A staging for layer 1.
// Tests the codegen-perturbation hypothesis for the agg 45->67us regression.
// ---------------------------------------------------------------------------

#define R_REL 8

typedef unsigned short ushort_t;
typedef short short8 __attribute__((ext_vector_type(8)));
typedef float f32x4 __attribute__((ext_vector_type(4)));

#define MFMA(a, b, c) __builtin_amdgcn_mfma_f32_16x16x32_bf16(a, b, c, 0, 0, 0)

static __device__ __forceinline__ unsigned short f2bf(float f) {
    unsigned int u = __float_as_uint(f);
    u = (u + 0x7FFF + ((u >> 16) & 1)) >> 16;   // round-to-nearest-even
    return (unsigned short)u;
}
static __device__ __forceinline__ float bf2f(unsigned short h) {
    return __uint_as_float(((unsigned int)h) << 16);
}

// ---- merged weight convert + transpose: 6 arrays, f32 [G][K][64] -> bf16 [G][64][K]
struct WcvtA {
    const float* src[6];
    ushort_t*    dst[6];
    int          end[6];
    int          K[6];
};
__global__ void wcvt6_kernel(WcvtA a, int total)
{
    int i = blockIdx.x * 256 + threadIdx.x;
    if (i >= total) return;
    int s = 0;
    while (i >= a.end[s]) ++s;
    int j = i - (s ? a.end[s - 1] : 0);
    int K = a.K[s];
    int g = j / (K * 64), rem = j % (K * 64), k = rem >> 6, c = rem & 63;
    a.dst[s][(size_t)g * 64 * K + (size_t)c * K + k] = f2bf(a.src[s][j]);
}

// ---- MFMA GEMM, A staged once per block, 3 output tiles per block.
template<int K, bool AF32>
__global__ __launch_bounds__(256)
void mgemm3_kernel(const void* __restrict__ Av, int n,
                   const ushort_t* __restrict__ WT, const ushort_t* __restrict__ RT,
                   const float* __restrict__ bias,
                   ushort_t* __restrict__ H, float* __restrict__ accb)
{
    __shared__ ushort_t As[64][K + 8];
    __shared__ ushort_t Bs[64][K + 8];
    __shared__ float    Ct[64][68];

    const int row0 = blockIdx.x * 64;
    const int tid = threadIdx.x;
    const int KB = K >> 3;

    for (int i = tid; i < 64 * KB; i += 256) {
        int r = i / KB, k8 = (i % KB) << 3;
        if (AF32) {
            const float* Af = (const float*)Av;
            float4 f0 = make_float4(0.f, 0.f, 0.f, 0.f), f1 = f0;
            if (row0 + r < n) {
                f0 = *(const float4*)&Af[(size_t)(row0 + r) * K + k8];
                f1 = *(const float4*)&Af[(size_t)(row0 + r) * K + k8 + 4];
            }
            ushort_t t[8] = {f2bf(f0.x), f2bf(f0.y), f2bf(f0.z), f2bf(f0.w),
                             f2bf(f1.x), f2bf(f1.y), f2bf(f1.z), f2bf(f1.w)};
            *(uint4*)&As[r][k8] = *(const uint4*)t;
        } else {
            const ushort_t* Ab = (const ushort_t*)Av;
            uint4 av = make_uint4(0u, 0u, 0u, 0u);
            if (row0 + r < n) av = *(const uint4*)&Ab[(size_t)(row0 + r) * K + k8];
            *(uint4*)&As[r][k8] = av;
        }
    }

    const int wid  = tid >> 6;
    const int lane = tid & 63;
    const int wr = (wid >> 1) << 5;
    const int wc = (wid & 1) << 5;
    const int fr = lane & 15;
    const int kg = (lane >> 4) << 3;
    const int rbase = (lane >> 4) << 2;

    for (int j = 0; j < 3; ++j) {
        const int r = blockIdx.y * 3 + j;
        const ushort_t* Bsrc = (r < R_REL) ? (WT + (size_t)r * 64 * K) : RT;

        __syncthreads();
        for (int i = tid; i < 64 * KB; i += 256) {
            int rr = i / KB, k8 = (i % KB) << 3;
            *(uint4*)&Bs[rr][k8] = *(const uint4*)&Bsrc[(size_t)rr * K + k8];
        }
        __syncthreads();

        f32x4 acc[2][2] = {};
        #pragma unroll
        for (int k0 = 0; k0 < K; k0 += 32) {
            short8 a0 = *(const short8*)&As[wr + fr     ][k0 + kg];
            short8 a1 = *(const short8*)&As[wr + 16 + fr][k0 + kg];
            short8 b0 = *(const short8*)&Bs[wc + fr     ][k0 + kg];
            short8 b1 = *(const short8*)&Bs[wc + 16 + fr][k0 + kg];
            acc[0][0] = MFMA(a0, b0, acc[0][0]);
            acc[0][1] = MFMA(a0, b1, acc[0][1]);
            acc[1][0] = MFMA(a1, b0, acc[1][0]);
            acc[1][1] = MFMA(a1, b1, acc[1][1]);
        }
        __syncthreads();

        #pragma unroll
        for (int m = 0; m < 2; ++m)
            #pragma unroll
            for (int nn = 0; nn < 2; ++nn)
                #pragma unroll
                for (int q = 0; q < 4; ++q)
                    Ct[wr + m * 16 + rbase + q][wc + nn * 16 + fr] = acc[m][nn][q];
        __syncthreads();

        if (r < R_REL) {
            const int cb = r << 6;
            for (int i = tid; i < 64 * 8; i += 256) {
                int rr = i >> 3, c8 = (i & 7) << 3;
                if (row0 + rr < n) {
                    ushort_t t[8];
                    #pragma unroll
                    for (int q = 0; q < 8; ++q) t[q] = f2bf(Ct[rr][c8 + q]);
                    *(uint4*)&H[(size_t)(row0 + rr) * 512 + cb + c8] = *(const uint4*)t;
                }
            }
        } else {
            for (int i = tid; i < 64 * 16; i += 256) {
                int rr = i >> 4, c4 = (i & 15) << 2;
                if (row0 + rr < n) {
                    float4 o;
                    o.x = Ct[rr][c4 + 0] + bias[c4 + 0];
                    o.y = Ct[rr][c4 + 1] + bias[c4 + 1];
                    o.z = Ct[rr][c4 + 2] + bias[c4 + 2];
                    o.w = Ct[rr][c4 + 3] + bias[c4 + 3];
                    *(float4*)&accb[(size_t)(row0 + rr) * 64 + c4] = o;
                }
            }
        }
    }
}

// ---- CSR build -------------------------------------------------------------
__global__ void count_kernel(const int* __restrict__ ei, const int* __restrict__ et,
                             int* __restrict__ cnt, int E)
{
    int e = blockIdx.x * 256 + threadIdx.x;
    if (e < E) atomicAdd(&cnt[(size_t)ei[E + e] * R_REL + et[e]], 1);
}

__global__ void invdeg_scan_kernel(float* __restrict__ inv, int* __restrict__ deg,
                                   int* __restrict__ offs, int* __restrict__ partials,
                                   int N)
{
    __shared__ int sm[256];
    int i = blockIdx.x * 256 + threadIdx.x;
    int tot = 0;
    if (i < N) {
        const int* c = (const int*)inv;
        float out[R_REL];
        #pragma unroll
        for (int r = 0; r < R_REL; ++r) {
            int cc = c[(size_t)i * R_REL + r];
            tot += cc;
            out[r] = 1.0f / (float)(cc > 1 ? cc : 1);
        }
        #pragma unroll
        for (int r = 0; r < R_REL; ++r) inv[(size_t)i * R_REL + r] = out[r];
        deg[i] = tot;
    }
    sm[threadIdx.x] = tot;
    __syncthreads();
    for (int off = 1; off < 256; off <<= 1) {
        int t = (threadIdx.x >= off) ? sm[threadIdx.x - off] : 0;
        __syncthreads();
        sm[threadIdx.x] += t;
        __syncthreads();
    }
    if (i < N) offs[i] = sm[threadIdx.x] - tot;
    if (threadIdx.x == 255) partials[blockIdx.x] = sm[255];
}

__global__ void scan2_kernel(int* __restrict__ partials, int P)
{
    __shared__ int sm[256];
    __shared__ int carry;
    if (threadIdx.x == 0) carry = 0;
    __syncthreads();
    for (int base = 0; base < P; base += 256) {
        int i = base + threadIdx.x;
        int c = (i < P) ? partials[i] : 0;
        sm[threadIdx.x] = c;
        __syncthreads();
        for (int off = 1; off < 256; off <<= 1) {
            int t = (threadIdx.x >= off) ? sm[threadIdx.x - off] : 0;
            __syncthreads();
            sm[threadIdx.x] += t;
            __syncthreads();
        }
        int incl = sm[threadIdx.x];
        int cold = carry;
        if (i < P) partials[i] = incl - c + cold;
        __syncthreads();
        if (threadIdx.x == 0) carry = cold + sm[255];
        __syncthreads();
    }
}

__global__ void scan3_kernel(int* __restrict__ offs, const int* __restrict__ partials, int N)
{
    int i = blockIdx.x * 256 + threadIdx.x;
    if (i < N) offs[i] += partials[blockIdx.x];
}

// scatter: ep[pos] = {src*512 + r*64, bits(1/cnt(dst,rel))}
__global__ void fill3_kernel(const int* __restrict__ ei, const int* __restrict__ et,
                             const int* __restrict__ offs, int* __restrict__ cursor,
                             const float* __restrict__ inv,
                             int2* __restrict__ ep, int E)
{
    int e = blockIdx.x * 256 + threadIdx.x;
    if (e >= E) return;
    int d = ei[E + e];
    int r = et[e];
    int pos = offs[d] + atomicAdd(&cursor[d], 1);
    ep[pos] = make_int2(ei[e] * 512 + r * 64,
                        __float_as_int(inv[(size_t)d * R_REL + r]));
}

// ---- one wave per dst, 8 edges in flight (16-lane subgroups, uint2/lane),
// shfl_xor reduce, fused ReLU+BN -> xout (bf16).  [verbatim r7 agg3]
__global__ __launch_bounds__(256)
void agg3_kernel(const int2* __restrict__ ep,
                 const int* __restrict__ offs, const int* __restrict__ deg,
                 const ushort_t* __restrict__ H, const float* __restrict__ accb,
                 const float* __restrict__ g, const float* __restrict__ b,
                 const float* __restrict__ rm, const float* __restrict__ rv,
                 ushort_t* __restrict__ xout, int N)
{
    const int lane = threadIdx.x & 63;
    const int d = (blockIdx.x * 256 + threadIdx.x) >> 6;
    if (d >= N) return;

    const int sub = lane >> 4;
    const int fl  = lane & 15;
    const int n0 = offs[d];
    const int dg = deg[d];

    float s0 = 0.f, s1 = 0.f, s2 = 0.f, s3 = 0.f;
    int k = 0;

    for (; k + 8 <= dg; k += 8) {
        int2 eA = ep[n0 + k + sub];
        int2 eB = ep[n0 + k + 4 + sub];
        uint2 hA = *(const uint2*)&H[(size_t)eA.x + (fl << 2)];
        uint2 hB = *(const uint2*)&H[(size_t)eB.x + (fl << 2)];
        float wA = __int_as_float(eA.y);
        float wB = __int_as_float(eB.y);
        s0 += bf2f((ushort_t)(hA.x & 0xFFFF)) * wA + bf2f((ushort_t)(hB.x & 0xFFFF)) * wB;
        s1 += bf2f((ushort_t)(hA.x >> 16))    * wA + bf2f((ushort_t)(hB.x >> 16))    * wB;
        s2 += bf2f((ushort_t)(hA.y & 0xFFFF)) * wA + bf2f((ushort_t)(hB.y & 0xFFFF)) * wB;
        s3 += bf2f((ushort_t)(hA.y >> 16))    * wA + bf2f((ushort_t)(hB.y >> 16))    * wB;
    }
    for (; k + 4 <= dg; k += 4) {
        int2 eA = ep[n0 + k + sub];
        uint2 hA = *(const uint2*)&H[(size_t)eA.x + (fl << 2)];
        float wA = __int_as_float(eA.y);
        s0 += bf2f((ushort_t)(hA.x & 0xFFFF)) * wA;
        s1 += bf2f((ushort_t)(hA.x >> 16))    * wA;
        s2 += bf2f((ushort_t)(hA.y & 0xFFFF)) * wA;
        s3 += bf2f((ushort_t)(hA.y >> 16))    * wA;
    }
    if (k < dg && sub < dg - k) {   // tail: 1..3 edges
        int2 eA = ep[n0 + k + sub];
        uint2 hA = *(const uint2*)&H[(size_t)eA.x + (fl << 2)];
        float wA = __int_as_float(eA.y);
        s0 += bf2f((ushort_t)(hA.x & 0xFFFF)) * wA;
        s1 += bf2f((ushort_t)(hA.x >> 16))    * wA;
        s2 += bf2f((ushort_t)(hA.y & 0xFFFF)) * wA;
        s3 += bf2f((ushort_t)(hA.y >> 16))    * wA;
    }

    s0 += __shfl_xor(s0, 16); s1 += __shfl_xor(s1, 16);
    s2 += __shfl_xor(s2, 16); s3 += __shfl_xor(s3, 16);
    s0 += __shfl_xor(s0, 32); s1 += __shfl_xor(s1, 32);
    s2 += __shfl_xor(s2, 32); s3 += __shfl_xor(s3, 32);

    if (sub == 0) {
        const int c4 = fl << 2;
        float4 a  = *(const float4*)&accb[(size_t)d * 64 + c4];
        float4 gm = *(const float4*)&g[c4];
        float4 bt = *(const float4*)&b[c4];
        float4 mu = *(const float4*)&rm[c4];
        float4 vr = *(const float4*)&rv[c4];
        float t0 = a.x + s0, t1 = a.y + s1, t2 = a.z + s2, t3 = a.w + s3;
        t0 = t0 > 0.f ? t0 : 0.f;  t1 = t1 > 0.f ? t1 : 0.f;
        t2 = t2 > 0.f ? t2 : 0.f;  t3 = t3 > 0.f ? t3 : 0.f;
        t0 = (t0 - mu.x) * rsqrtf(vr.x + 1e-5f) * gm.x + bt.x;
        t1 = (t1 - mu.y) * rsqrtf(vr.y + 1e-5f) * gm.y + bt.y;
        t2 = (t2 - mu.z) * rsqrtf(vr.z + 1e-5f) * gm.z + bt.z;
        t3 = (t3 - mu.w) * rsqrtf(vr.w + 1e-5f) * gm.w + bt.w;
        ushort_t o[4] = {f2bf(t0), f2bf(t1), f2bf(t2), f2bf(t3)};
        *(uint2*)&xout[(size_t)d * 64 + c4] = *(const uint2*)o;
    }
}

// ---- final linear: out[n][c] = sum_k h[n][k]*Wl[k][c] + bl[c]   (C=16)
__global__ __launch_bounds__(256)
void lin_kernel(const ushort_t* __restrict__ h, const float* __restrict__ Wl,
                const float* __restrict__ bl, float* __restrict__ out, int N)
{
    __shared__ float w[64 * 16];
    __shared__ float bb[16];
    for (int i = threadIdx.x; i < 64 * 16; i += 256) w[i] = Wl[i];
    if (threadIdx.x < 16) bb[threadIdx.x] = bl[threadIdx.x];
    __syncthreads();

    int idx = blockIdx.x * 256 + threadIdx.x;
    if (idx >= N * 16) return;
    int node = idx >> 4, c = idx & 15;
    float s = bb[c];
    const ushort_t* hr = h + (size_t)node * 64;
    #pragma unroll 16
    for (int k = 0; k < 64; ++k) s += bf2f(hr[k]) * w[k * 16 + c];
    out[idx] = s;
}

extern "C" void kernel_launch(void* const* d_in, const int* in_sizes, int n_in,
                              void* d_out, int out_size, void* d_ws, size_t ws_size,
                              hipStream_t stream)
{
    const float* x  = (const float*)d_in[0];
    const int*   ei = (const int*)d_in[1];
    const int*   et = (const int*)d_in[2];
    const float* W[3]    = {(const float*)d_in[3], (const float*)d_in[6], (const float*)d_in[9]};
    const float* root[3] = {(const float*)d_in[4], (const float*)d_in[7], (const float*)d_in[10]};
    const float* bias[3] = {(const float*)d_in[5], (const float*)d_in[8], (const float*)d_in[11]};
    const float* gamma[3] = {(const float*)d_in[12], (const float*)d_in[16], (const float*)d_in[20]};
    const float* beta[3]  = {(const float*)d_in[13], (const float*)d_in[17], (const float*)d_in[21]};
    const float* rm[3]    = {(const float*)d_in[14], (const float*)d_in[18], (const float*)d_in[22]};
    const float* rv[3]    = {(const float*)d_in[15], (const float*)d_in[19], (const float*)d_in[23]};
    const float* Wl = (const float*)d_in[24];
    const float* bl = (const float*)d_in[25];

    const int N = in_sizes[0] / 128;
    const int E = in_sizes[2];
    const int K1 = 128;

    // ---- workspace layout (all 16B aligned) ----
    char* p = (char*)d_ws;
    float*   inv  = (float*)p;    p += (size_t)N * R_REL * 4;
    ushort_t* Hbuf = (ushort_t*)p; p += (size_t)N * 512 * 2;
    float*   accb = (float*)p;    p += (size_t)N * 64 * 4;
    ushort_t* xb  = (ushort_t*)p; p += (size_t)N * 64 * 2;
    ushort_t* wt0 = (ushort_t*)p; p += (size_t)R_REL * 64 * K1 * 2;
    ushort_t* wt1 = (ushort_t*)p; p += (size_t)R_REL * 64 * 64 * 2;
    ushort_t* wt2 = (ushort_t*)p; p += (size_t)R_REL * 64 * 64 * 2;
    ushort_t* rt0 = (ushort_t*)p; p += (size_t)64 * K1 * 2;
    ushort_t* rt1 = (ushort_t*)p; p += (size_t)64 * 64 * 2;
    ushort_t* rt2 = (ushort_t*)p; p += (size_t)64 * 64 * 2;
    int*   offs    = (int*)p;     p += (size_t)N * 4;
    int*   deg     = (int*)p;     p += (size_t)N * 4;
    int*   cursor  = (int*)p;     p += (size_t)N * 4;
    int2*  ep      = (int2*)p;    p += (size_t)E * 8;
    int*   partials = (int*)p;

    const ushort_t* wt[3] = {wt0, wt1, wt2};
    const ushort_t* rt[3] = {rt0, rt1, rt2};

    const int gxN = (N + 255) / 256;

    // ---- weight conversion (one kernel) ----
    {
        WcvtA a;
        a.src[0] = W[0];   a.dst[0] = wt0; a.K[0] = K1;
        a.src[1] = W[1];   a.dst[1] = wt1; a.K[1] = 64;
        a.src[2] = W[2];   a.dst[2] = wt2; a.K[2] = 64;
        a.src[3] = root[0]; a.dst[3] = rt0; a.K[3] = K1;
        a.src[4] = root[1]; a.dst[4] = rt1; a.K[4] = 64;
        a.src[5] = root[2]; a.dst[5] = rt2; a.K[5] = 64;
        int sizes[6] = {R_REL * K1 * 64, R_REL * 64 * 64, R_REL * 64 * 64,
                        K1 * 64, 64 * 64, 64 * 64};
        int acc = 0;
        for (int i = 0; i < 6; ++i) { acc += sizes[i]; a.end[i] = acc; }
        wcvt6_kernel<<<(acc + 255) / 256, 256, 0, stream>>>(a, acc);
    }

    // ---- CSR build ----
    hipMemsetAsync(inv, 0, (size_t)N * R_REL * 4, stream);
    hipMemsetAsync(cursor, 0, (size_t)N * 4, stream);
    count_kernel<<<(E + 255) / 256, 256, 0, stream>>>(ei, et, (int*)inv, E);
    invdeg_scan_kernel<<<gxN, 256, 0, stream>>>(inv, deg, offs, partials, N);
    scan2_kernel<<<1, 256, 0, stream>>>(partials, gxN);
    scan3_kernel<<<gxN, 256, 0, stream>>>(offs, partials, N);
    fill3_kernel<<<(E + 255) / 256, 256, 0, stream>>>(ei, et, offs, cursor, inv, ep, E);

    // ---- 3 RGCN layers ----
    const int gx = (N + 63) / 64;
    const int gagg = (N * 64 + 255) / 256;
    const ushort_t* cur = nullptr;
    for (int layer = 0; layer < 3; ++layer) {
        if (layer == 0)
            mgemm3_kernel<128, true><<<dim3(gx, 3), 256, 0, stream>>>(
                (const void*)x, N, wt[0], rt[0], bias[0], Hbuf, accb);
        else
            mgemm3_kernel<64, false><<<dim3(gx, 3), 256, 0, stream>>>(
                (const void*)cur, N, wt[layer], rt[layer], bias[layer], Hbuf, accb);
        agg3_kernel<<<gagg, 256, 0, stream>>>(
            ep, offs, deg, Hbuf, accb,
            gamma[layer], beta[layer], rm[layer], rv[layer], xb, N);
        cur = xb;
    }

    lin_kernel<<<(N * 16 + 255) / 256, 256, 0, stream>>>(cur, Wl, bl, (float*)d_out, N);
}